// Round 1
// baseline (20744.879 us; speedup 1.0000x reference)
//
#include <hip/hip_runtime.h>

#define NN 50000
#define NE 1600000
#define H 64

__device__ __forceinline__ float silu_f(float x) {
    return x / (1.0f + __expf(-x));
}

// ---------------- deg = segment_sum(ones, row) ----------------
__global__ void k_deg(const int* __restrict__ edges, float* __restrict__ deg) {
    int e = blockIdx.x * blockDim.x + threadIdx.x;
    if (e >= NE) return;
    atomicAdd(&deg[edges[e]], 1.0f);
}

// ---------------- h = his @ emb_w + emb_b ----------------
__global__ void k_embed(const float* __restrict__ his, const float* __restrict__ w,
                        const float* __restrict__ b, float* __restrict__ h) {
    int t = blockIdx.x * blockDim.x + threadIdx.x;
    if (t >= NN * H) return;
    int n = t >> 6, j = t & 63;
    float acc = b[j];
#pragma unroll
    for (int i = 0; i < 16; i++) acc = fmaf(his[n * 16 + i], w[i * H + j], acc);
    h[t] = acc;
}

// ---------------- per-node precompute: pre_a = h@Wa, pre_b = h@Wb, vel_scale ----------------
// one node per wave, lane = output channel j
__global__ void k_node_pre(const float* __restrict__ h, const float* __restrict__ e_w1,
                           const float* __restrict__ v_w1, const float* __restrict__ v_b1,
                           const float* __restrict__ v_w2, const float* __restrict__ v_b2,
                           float* __restrict__ pre_a, float* __restrict__ pre_b,
                           float* __restrict__ vel) {
    int t = blockIdx.x * blockDim.x + threadIdx.x;
    int n = t >> 6, j = t & 63;
    if (n >= NN) return;
    n = __builtin_amdgcn_readfirstlane(n);
    float a = 0.f, b = 0.f, c = v_b1[j];
#pragma unroll
    for (int i = 0; i < H; i++) {
        float hi = h[n * H + i];
        a = fmaf(hi, e_w1[i * H + j], a);
        b = fmaf(hi, e_w1[(H + i) * H + j], b);
        c = fmaf(hi, v_w1[i * H + j], c);
    }
    pre_a[n * H + j] = a;
    pre_b[n * H + j] = b;
    float tv = silu_f(c) * v_w2[j];
#pragma unroll
    for (int k = 32; k >= 1; k >>= 1) tv += __shfl_xor(tv, k, 64);
    if (j == 0) vel[n] = tv + v_b2[0];
}

// ---------------- fused per-edge kernel ----------------
__global__ void __launch_bounds__(256) k_edge(
    const float* __restrict__ xw, const float* __restrict__ pre_a,
    const float* __restrict__ pre_b, const float* __restrict__ edge_attr,
    const int* __restrict__ edges,
    const float* __restrict__ e_w1, const float* __restrict__ e_b1,
    const float* __restrict__ e_w2, const float* __restrict__ e_b2,
    const float* __restrict__ c_w1, const float* __restrict__ c_b1,
    const float* __restrict__ c_w2,
    float* __restrict__ m_agg, float* __restrict__ coord_agg) {
    int e = blockIdx.x * blockDim.x + threadIdx.x;
    if (e >= NE) return;
    int row = edges[e];
    int col = edges[NE + e];
    float dx = xw[row * 3 + 0] - xw[col * 3 + 0];
    float dy = xw[row * 3 + 1] - xw[col * 3 + 1];
    float dz = xw[row * 3 + 2] - xw[col * 3 + 2];
    float radial = dx * dx + dy * dy + dz * dz;
    float ea0 = edge_attr[e * 2 + 0];
    float ea1 = edge_attr[e * 2 + 1];

    const float* wr  = e_w1 + 128 * H;  // radial row
    const float* we0 = e_w1 + 129 * H;  // edge_attr rows
    const float* we1 = e_w1 + 130 * H;

    float m1[H];
    // stage 1: first edge-MLP layer (h-parts pre-gathered) + SiLU
#pragma unroll
    for (int j4 = 0; j4 < H / 4; j4++) {
        float4 pa = *reinterpret_cast<const float4*>(pre_a + row * H + j4 * 4);
        float4 pb = *reinterpret_cast<const float4*>(pre_b + col * H + j4 * 4);
        float pav[4] = {pa.x, pa.y, pa.z, pa.w};
        float pbv[4] = {pb.x, pb.y, pb.z, pb.w};
#pragma unroll
        for (int k = 0; k < 4; k++) {
            int j = j4 * 4 + k;
            float tt = pav[k] + pbv[k] + e_b1[j];
            tt = fmaf(radial, wr[j], tt);
            tt = fmaf(ea0, we0[j], tt);
            tt = fmaf(ea1, we1[j], tt);
            m1[j] = silu_f(tt);
        }
    }
    // stage 2: m = silu(m1 @ e_w2 + e_b2)
    float acc[H];
#pragma unroll
    for (int j = 0; j < H; j++) acc[j] = e_b2[j];
#pragma unroll
    for (int i = 0; i < H; i++) {
        float mi = m1[i];
#pragma unroll
        for (int j = 0; j < H; j++) acc[j] = fmaf(mi, e_w2[i * H + j], acc[j]);
    }
#pragma unroll
    for (int j = 0; j < H; j++) m1[j] = silu_f(acc[j]);  // m1 now holds m
    // stage 3: c1 = silu(m @ c_w1 + c_b1)
#pragma unroll
    for (int j = 0; j < H; j++) acc[j] = c_b1[j];
#pragma unroll
    for (int i = 0; i < H; i++) {
        float mi = m1[i];
#pragma unroll
        for (int j = 0; j < H; j++) acc[j] = fmaf(mi, c_w1[i * H + j], acc[j]);
    }
    // stage 4: s = c1 @ c_w2 ; trans = diff * s
    float s = 0.f;
#pragma unroll
    for (int j = 0; j < H; j++) s = fmaf(silu_f(acc[j]), c_w2[j], s);

    atomicAdd(&coord_agg[row * 3 + 0], dx * s);
    atomicAdd(&coord_agg[row * 3 + 1], dy * s);
    atomicAdd(&coord_agg[row * 3 + 2], dz * s);
#pragma unroll
    for (int j = 0; j < H; j++) atomicAdd(&m_agg[row * H + j], m1[j]);
}

// ---------------- per-node update: v, x, node MLP, h ----------------
// one node per wave, lane = channel j
__global__ void k_node_post(float* __restrict__ h, const float* __restrict__ m_agg,
                            const float* __restrict__ coord_agg, const float* __restrict__ deg,
                            const float* __restrict__ vel,
                            const float* __restrict__ n_w1, const float* __restrict__ n_b1,
                            const float* __restrict__ n_w2, const float* __restrict__ n_b2,
                            float* __restrict__ xw, float* __restrict__ vw) {
    int t = blockIdx.x * blockDim.x + threadIdx.x;
    int n = t >> 6, j = t & 63;
    if (n >= NN) return;
    n = __builtin_amdgcn_readfirstlane(n);
    float acc = n_b1[j];
#pragma unroll
    for (int i = 0; i < H; i++) acc = fmaf(h[n * H + i], n_w1[i * H + j], acc);
#pragma unroll
    for (int i = 0; i < H; i++) acc = fmaf(m_agg[n * H + i], n_w1[(H + i) * H + j], acc);
    float tj = silu_f(acc);
    float upd = n_b2[j];
#pragma unroll
    for (int i = 0; i < H; i++) upd = fmaf(__shfl(tj, i, 64), n_w2[i * H + j], upd);
    float hj = h[n * H + j];
    h[n * H + j] = 2.f * hj + upd;
    if (j < 3) {
        float d = fmaxf(deg[n], 1.0f);
        float vv = vw[n * 3 + j];
        vv = vv + coord_agg[n * 3 + j] / d + vel[n] * vv;
        vw[n * 3 + j] = vv;
        xw[n * 3 + j] += vv;
    }
}

// ---------------- pack outputs: x | h | v ----------------
__global__ void k_pack(const float* __restrict__ xw, const float* __restrict__ h,
                       const float* __restrict__ vw, float* __restrict__ out) {
    int t = blockIdx.x * blockDim.x + threadIdx.x;
    if (t >= NN * 70) return;
    if (t < NN * 3) out[t] = xw[t];
    else if (t < NN * 3 + NN * H) out[t] = h[t - NN * 3];
    else out[t] = vw[t - (NN * 3 + NN * H)];
}

extern "C" void kernel_launch(void* const* d_in, const int* in_sizes, int n_in,
                              void* d_out, int out_size, void* d_ws, size_t ws_size,
                              hipStream_t stream) {
    const float* his       = (const float*)d_in[0];
    const float* x         = (const float*)d_in[1];
    const float* v         = (const float*)d_in[2];
    const float* edge_attr = (const float*)d_in[3];
    const int*   edges     = (const int*)d_in[4];
    const float* emb_w = (const float*)d_in[5];
    const float* emb_b = (const float*)d_in[6];
    const float* e_w1  = (const float*)d_in[7];
    const float* e_b1  = (const float*)d_in[8];
    const float* e_w2  = (const float*)d_in[9];
    const float* e_b2  = (const float*)d_in[10];
    const float* c_w1  = (const float*)d_in[11];
    const float* c_b1  = (const float*)d_in[12];
    const float* c_w2  = (const float*)d_in[13];
    const float* n_w1  = (const float*)d_in[14];
    const float* n_b1  = (const float*)d_in[15];
    const float* n_w2  = (const float*)d_in[16];
    const float* n_b2  = (const float*)d_in[17];
    const float* v_w1  = (const float*)d_in[18];
    const float* v_b1  = (const float*)d_in[19];
    const float* v_w2  = (const float*)d_in[20];
    const float* v_b2  = (const float*)d_in[21];

    float* ws = (float*)d_ws;
    float* xw        = ws;                    // N*3
    float* vw        = xw + NN * 3;           // N*3
    float* h         = vw + NN * 3;           // N*64
    float* pre_a     = h + NN * H;            // N*64
    float* pre_b     = pre_a + NN * H;        // N*64
    float* vel       = pre_b + NN * H;        // N
    float* m_agg     = vel + NN;              // N*64
    float* coord_agg = m_agg + NN * H;        // N*3
    float* deg       = coord_agg + NN * 3;    // N

    hipMemcpyAsync(xw, x, NN * 3 * sizeof(float), hipMemcpyDeviceToDevice, stream);
    hipMemcpyAsync(vw, v, NN * 3 * sizeof(float), hipMemcpyDeviceToDevice, stream);
    hipMemsetAsync(deg, 0, NN * sizeof(float), stream);
    k_deg<<<(NE + 255) / 256, 256, 0, stream>>>(edges, deg);
    k_embed<<<(NN * H + 255) / 256, 256, 0, stream>>>(his, emb_w, emb_b, h);

    for (int layer = 0; layer < 3; layer++) {
        hipMemsetAsync(m_agg, 0, NN * H * sizeof(float), stream);
        hipMemsetAsync(coord_agg, 0, NN * 3 * sizeof(float), stream);
        k_node_pre<<<(NN * H + 255) / 256, 256, 0, stream>>>(
            h, e_w1, v_w1, v_b1, v_w2, v_b2, pre_a, pre_b, vel);
        k_edge<<<(NE + 255) / 256, 256, 0, stream>>>(
            xw, pre_a, pre_b, edge_attr, edges,
            e_w1, e_b1, e_w2, e_b2, c_w1, c_b1, c_w2, m_agg, coord_agg);
        k_node_post<<<(NN * H + 255) / 256, 256, 0, stream>>>(
            h, m_agg, coord_agg, deg, vel, n_w1, n_b1, n_w2, n_b2, xw, vw);
    }
    k_pack<<<(NN * 70 + 255) / 256, 256, 0, stream>>>(xw, h, vw, (float*)d_out);
}

// Round 2
// 19557.397 us; speedup vs baseline: 1.0607x; 1.0607x over previous
//
#include <hip/hip_runtime.h>

#define NN 50000
#define NE 1600000
#define H 64

__device__ __forceinline__ float silu_f(float x) {
    return x / (1.0f + __expf(-x));
}

// ---------------- CSR build: count, scan, scatter ----------------
__global__ void k_count(const int* __restrict__ edges, int* __restrict__ cnt) {
    int e = blockIdx.x * blockDim.x + threadIdx.x;
    if (e >= NE) return;
    atomicAdd(&cnt[edges[e]], 1);
}

// single block, 1024 threads: exclusive scan of cnt -> off[NN+1], copy to cursor
__global__ void k_scan(const int* __restrict__ cnt, int* __restrict__ off,
                       int* __restrict__ cursor) {
    __shared__ int part[1024];
    const int PER = (NN + 1023) / 1024;  // 49
    int t = threadIdx.x;
    int base = t * PER;
    int s = 0;
    for (int i = 0; i < PER; i++) {
        int idx = base + i;
        if (idx < NN) s += cnt[idx];
    }
    part[t] = s;
    __syncthreads();
    for (int d = 1; d < 1024; d <<= 1) {
        int tmp = (t >= d) ? part[t - d] : 0;
        __syncthreads();
        part[t] += tmp;
        __syncthreads();
    }
    int run = (t == 0) ? 0 : part[t - 1];
    for (int i = 0; i < PER; i++) {
        int idx = base + i;
        if (idx < NN) {
            off[idx] = run;
            cursor[idx] = run;
            run += cnt[idx];
        }
    }
    if (t == 1023) off[NN] = part[1023];
}

__global__ void k_scatter(const int* __restrict__ edges, int* __restrict__ cursor,
                          int* __restrict__ sorted) {
    int e = blockIdx.x * blockDim.x + threadIdx.x;
    if (e >= NE) return;
    int r = edges[e];
    int p = atomicAdd(&cursor[r], 1);
    sorted[p] = e;
}

// ---------------- h = his @ emb_w + emb_b ----------------
__global__ void k_embed(const float* __restrict__ his, const float* __restrict__ w,
                        const float* __restrict__ b, float* __restrict__ h) {
    int t = blockIdx.x * blockDim.x + threadIdx.x;
    if (t >= NN * H) return;
    int n = t >> 6, j = t & 63;
    float acc = b[j];
#pragma unroll
    for (int i = 0; i < 16; i++) acc = fmaf(his[n * 16 + i], w[i * H + j], acc);
    h[t] = acc;
}

// ---------------- per-node precompute: pre_a = h@Wa, pre_b = h@Wb, vel_scale ----------------
__global__ void k_node_pre(const float* __restrict__ h, const float* __restrict__ e_w1,
                           const float* __restrict__ v_w1, const float* __restrict__ v_b1,
                           const float* __restrict__ v_w2, const float* __restrict__ v_b2,
                           float* __restrict__ pre_a, float* __restrict__ pre_b,
                           float* __restrict__ vel) {
    int t = blockIdx.x * blockDim.x + threadIdx.x;
    int n = t >> 6, j = t & 63;
    if (n >= NN) return;
    n = __builtin_amdgcn_readfirstlane(n);
    float a = 0.f, b = 0.f, c = v_b1[j];
#pragma unroll
    for (int i = 0; i < H; i++) {
        float hi = h[n * H + i];
        a = fmaf(hi, e_w1[i * H + j], a);
        b = fmaf(hi, e_w1[(H + i) * H + j], b);
        c = fmaf(hi, v_w1[i * H + j], c);
    }
    pre_a[n * H + j] = a;
    pre_b[n * H + j] = b;
    float tv = silu_f(c) * v_w2[j];
#pragma unroll
    for (int k = 32; k >= 1; k >>= 1) tv += __shfl_xor(tv, k, 64);
    if (j == 0) vel[n] = tv + v_b2[0];
}

// ---------------- per-edge compute (sorted order, chunked): write m, trans ----------------
__global__ void __launch_bounds__(256) k_edge_chunk(
    const float* __restrict__ xw, const float* __restrict__ pre_a,
    const float* __restrict__ pre_b, const float* __restrict__ edge_attr,
    const int* __restrict__ edges, const int* __restrict__ sorted,
    const int* __restrict__ off, int n0, int n1,
    const float* __restrict__ e_w1, const float* __restrict__ e_b1,
    const float* __restrict__ e_w2, const float* __restrict__ e_b2,
    const float* __restrict__ c_w1, const float* __restrict__ c_b1,
    const float* __restrict__ c_w2,
    float* __restrict__ mbuf, float* __restrict__ transbuf) {
    int base = off[n0];
    int endk = off[n1];
    int t = blockIdx.x * blockDim.x + threadIdx.x;
    int k = base + t;
    if (k >= endk) return;
    int eid = sorted[k];
    int row = edges[eid];
    int col = edges[NE + eid];
    float dx = xw[row * 3 + 0] - xw[col * 3 + 0];
    float dy = xw[row * 3 + 1] - xw[col * 3 + 1];
    float dz = xw[row * 3 + 2] - xw[col * 3 + 2];
    float radial = dx * dx + dy * dy + dz * dz;
    float ea0 = edge_attr[eid * 2 + 0];
    float ea1 = edge_attr[eid * 2 + 1];

    const float* wr  = e_w1 + 128 * H;
    const float* we0 = e_w1 + 129 * H;
    const float* we1 = e_w1 + 130 * H;

    float m1[H];
#pragma unroll
    for (int j4 = 0; j4 < H / 4; j4++) {
        float4 pa = *reinterpret_cast<const float4*>(pre_a + row * H + j4 * 4);
        float4 pb = *reinterpret_cast<const float4*>(pre_b + col * H + j4 * 4);
        float pav[4] = {pa.x, pa.y, pa.z, pa.w};
        float pbv[4] = {pb.x, pb.y, pb.z, pb.w};
#pragma unroll
        for (int kk = 0; kk < 4; kk++) {
            int j = j4 * 4 + kk;
            float tt = pav[kk] + pbv[kk] + e_b1[j];
            tt = fmaf(radial, wr[j], tt);
            tt = fmaf(ea0, we0[j], tt);
            tt = fmaf(ea1, we1[j], tt);
            m1[j] = silu_f(tt);
        }
    }
    float acc[H];
#pragma unroll
    for (int j = 0; j < H; j++) acc[j] = e_b2[j];
#pragma unroll
    for (int i = 0; i < H; i++) {
        float mi = m1[i];
#pragma unroll
        for (int j = 0; j < H; j++) acc[j] = fmaf(mi, e_w2[i * H + j], acc[j]);
    }
#pragma unroll
    for (int j = 0; j < H; j++) m1[j] = silu_f(acc[j]);  // m1 now holds m
#pragma unroll
    for (int j = 0; j < H; j++) acc[j] = c_b1[j];
#pragma unroll
    for (int i = 0; i < H; i++) {
        float mi = m1[i];
#pragma unroll
        for (int j = 0; j < H; j++) acc[j] = fmaf(mi, c_w1[i * H + j], acc[j]);
    }
    float s = 0.f;
#pragma unroll
    for (int j = 0; j < H; j++) s = fmaf(silu_f(acc[j]), c_w2[j], s);

    float* mp = mbuf + (size_t)t * H;
#pragma unroll
    for (int j4 = 0; j4 < H / 4; j4++) {
        float4 v4 = {m1[j4 * 4 + 0], m1[j4 * 4 + 1], m1[j4 * 4 + 2], m1[j4 * 4 + 3]};
        *reinterpret_cast<float4*>(mp + j4 * 4) = v4;
    }
    transbuf[t * 3 + 0] = dx * s;
    transbuf[t * 3 + 1] = dy * s;
    transbuf[t * 3 + 2] = dz * s;
}

// ---------------- per-node gather + node MLP + v/x update (chunked, no atomics) ----------------
__global__ void k_post_chunk(
    const float* __restrict__ h_old, float* __restrict__ h_new,
    const float* __restrict__ mbuf, const float* __restrict__ transbuf,
    const int* __restrict__ off, int n0, int n1,
    const float* __restrict__ vel,
    const float* __restrict__ n_w1, const float* __restrict__ n_b1,
    const float* __restrict__ n_w2, const float* __restrict__ n_b2,
    const float* __restrict__ x_old, float* __restrict__ x_new,
    const float* __restrict__ v_old, float* __restrict__ v_new) {
    int t = blockIdx.x * blockDim.x + threadIdx.x;
    int n = n0 + (t >> 6);
    int j = t & 63;
    if (n >= n1) return;
    int base = __builtin_amdgcn_readfirstlane(off[n0]);
    int start = __builtin_amdgcn_readfirstlane(off[n]);
    int end = __builtin_amdgcn_readfirstlane(off[n + 1]);

    float macc = 0.f;
    for (int k = start; k < end; k++) macc += mbuf[(size_t)(k - base) * H + j];

    float tx = 0.f, ty = 0.f, tz = 0.f;
    for (int k0 = start; k0 < end; k0 += 64) {
        int k = k0 + j;
        if (k < end) {
            const float* tp = transbuf + (size_t)(k - base) * 3;
            tx += tp[0];
            ty += tp[1];
            tz += tp[2];
        }
    }
#pragma unroll
    for (int d = 32; d >= 1; d >>= 1) {
        tx += __shfl_xor(tx, d, 64);
        ty += __shfl_xor(ty, d, 64);
        tz += __shfl_xor(tz, d, 64);
    }
    float deg = fmaxf((float)(end - start), 1.0f);

    float acc = n_b1[j];
#pragma unroll
    for (int i = 0; i < H; i++) acc = fmaf(h_old[n * H + i], n_w1[i * H + j], acc);
#pragma unroll
    for (int i = 0; i < H; i++) acc = fmaf(__shfl(macc, i, 64), n_w1[(H + i) * H + j], acc);
    float tj = silu_f(acc);
    float upd = n_b2[j];
#pragma unroll
    for (int i = 0; i < H; i++) upd = fmaf(__shfl(tj, i, 64), n_w2[i * H + j], upd);
    float hj = h_old[n * H + j];
    h_new[n * H + j] = 2.f * hj + upd;
    if (j < 3) {
        float ca = ((j == 0) ? tx : (j == 1) ? ty : tz) / deg;
        float vv = v_old[n * 3 + j];
        vv = vv + ca + vel[n] * vv;
        v_new[n * 3 + j] = vv;
        x_new[n * 3 + j] = x_old[n * 3 + j] + vv;
    }
}

// ---------------- pack outputs: x | h | v ----------------
__global__ void k_pack(const float* __restrict__ xw, const float* __restrict__ h,
                       const float* __restrict__ vw, float* __restrict__ out) {
    int t = blockIdx.x * blockDim.x + threadIdx.x;
    if (t >= NN * 70) return;
    if (t < NN * 3) out[t] = xw[t];
    else if (t < NN * 3 + NN * H) out[t] = h[t - NN * 3];
    else out[t] = vw[t - (NN * 3 + NN * H)];
}

extern "C" void kernel_launch(void* const* d_in, const int* in_sizes, int n_in,
                              void* d_out, int out_size, void* d_ws, size_t ws_size,
                              hipStream_t stream) {
    const float* his       = (const float*)d_in[0];
    const float* x         = (const float*)d_in[1];
    const float* v         = (const float*)d_in[2];
    const float* edge_attr = (const float*)d_in[3];
    const int*   edges     = (const int*)d_in[4];
    const float* emb_w = (const float*)d_in[5];
    const float* emb_b = (const float*)d_in[6];
    const float* e_w1  = (const float*)d_in[7];
    const float* e_b1  = (const float*)d_in[8];
    const float* e_w2  = (const float*)d_in[9];
    const float* e_b2  = (const float*)d_in[10];
    const float* c_w1  = (const float*)d_in[11];
    const float* c_b1  = (const float*)d_in[12];
    const float* c_w2  = (const float*)d_in[13];
    const float* n_w1  = (const float*)d_in[14];
    const float* n_b1  = (const float*)d_in[15];
    const float* n_w2  = (const float*)d_in[16];
    const float* n_b2  = (const float*)d_in[17];
    const float* v_w1  = (const float*)d_in[18];
    const float* v_b1  = (const float*)d_in[19];
    const float* v_w2  = (const float*)d_in[20];
    const float* v_b2  = (const float*)d_in[21];

    char* wsb = (char*)d_ws;
    float* xA    = (float*)wsb;                 wsb += (size_t)NN * 3 * 4;
    float* xB    = (float*)wsb;                 wsb += (size_t)NN * 3 * 4;
    float* vA    = (float*)wsb;                 wsb += (size_t)NN * 3 * 4;
    float* vB    = (float*)wsb;                 wsb += (size_t)NN * 3 * 4;
    float* hA    = (float*)wsb;                 wsb += (size_t)NN * H * 4;
    float* hB    = (float*)wsb;                 wsb += (size_t)NN * H * 4;
    float* pre_a = (float*)wsb;                 wsb += (size_t)NN * H * 4;
    float* pre_b = (float*)wsb;                 wsb += (size_t)NN * H * 4;
    float* vel   = (float*)wsb;                 wsb += (size_t)NN * 4;
    int* cnt     = (int*)wsb;                   wsb += (size_t)NN * 4;
    int* off     = (int*)wsb;                   wsb += (size_t)(NN + 1) * 4;
    int* cursor  = (int*)wsb;                   wsb += (size_t)NN * 4;
    int* sorted  = (int*)wsb;                   wsb += (size_t)NE * 4;
    size_t fixedBytes = (size_t)(wsb - (char*)d_ws);

    // pick smallest chunk count whose scratch fits
    int NC = 32;
    size_t CAP = NE / 32 + NE / 32 / 8 + 4096;
    const int ncs[6] = {1, 2, 4, 8, 16, 32};
    for (int ci = 0; ci < 6; ci++) {
        int c = ncs[ci];
        size_t cap = (size_t)NE / c + (size_t)NE / c / 8 + 4096;
        if (fixedBytes + cap * (H + 3) * 4 <= ws_size) { NC = c; CAP = cap; break; }
    }
    float* mbuf     = (float*)wsb;              wsb += CAP * H * 4;
    float* transbuf = (float*)wsb;

    // ---- CSR build (once per call) ----
    hipMemsetAsync(cnt, 0, (size_t)NN * 4, stream);
    k_count<<<(NE + 255) / 256, 256, 0, stream>>>(edges, cnt);
    k_scan<<<1, 1024, 0, stream>>>(cnt, off, cursor);
    k_scatter<<<(NE + 255) / 256, 256, 0, stream>>>(edges, cursor, sorted);

    hipMemcpyAsync(xA, x, (size_t)NN * 3 * 4, hipMemcpyDeviceToDevice, stream);
    hipMemcpyAsync(vA, v, (size_t)NN * 3 * 4, hipMemcpyDeviceToDevice, stream);
    k_embed<<<(NN * H + 255) / 256, 256, 0, stream>>>(his, emb_w, emb_b, hA);

    float *x_cur = xA, *x_nxt = xB, *v_cur = vA, *v_nxt = vB, *h_cur = hA, *h_nxt = hB;
    int edge_blocks = (int)((CAP + 255) / 256);

    for (int layer = 0; layer < 3; layer++) {
        k_node_pre<<<(NN * H + 255) / 256, 256, 0, stream>>>(
            h_cur, e_w1, v_w1, v_b1, v_w2, v_b2, pre_a, pre_b, vel);
        for (int c = 0; c < NC; c++) {
            int n0 = (int)((long long)NN * c / NC);
            int n1 = (int)((long long)NN * (c + 1) / NC);
            k_edge_chunk<<<edge_blocks, 256, 0, stream>>>(
                x_cur, pre_a, pre_b, edge_attr, edges, sorted, off, n0, n1,
                e_w1, e_b1, e_w2, e_b2, c_w1, c_b1, c_w2, mbuf, transbuf);
            int nodes = n1 - n0;
            k_post_chunk<<<(nodes * 64 + 255) / 256, 256, 0, stream>>>(
                h_cur, h_nxt, mbuf, transbuf, off, n0, n1, vel,
                n_w1, n_b1, n_w2, n_b2, x_cur, x_nxt, v_cur, v_nxt);
        }
        float* tp;
        tp = x_cur; x_cur = x_nxt; x_nxt = tp;
        tp = v_cur; v_cur = v_nxt; v_nxt = tp;
        tp = h_cur; h_cur = h_nxt; h_nxt = tp;
    }
    k_pack<<<(NN * 70 + 255) / 256, 256, 0, stream>>>(x_cur, h_cur, v_cur, (float*)d_out);
}

// Round 3
// 3733.533 us; speedup vs baseline: 5.5564x; 5.2383x over previous
//
#include <hip/hip_runtime.h>

#define NN 50000
#define NE 1600000
#define H 64
#define NT (NE / 16)

typedef short bf16x8 __attribute__((ext_vector_type(8)));
typedef float f32x4 __attribute__((ext_vector_type(4)));

__device__ __forceinline__ float silu_f(float x) {
    return x / (1.0f + __expf(-x));
}
__device__ __forceinline__ float silu_fast(float x) {
    return x * __builtin_amdgcn_rcpf(1.0f + __expf(-x));
}
__device__ __forceinline__ unsigned short f2bf(float f) {
    union { float f; unsigned u; } v; v.f = f;
    unsigned r = v.u + 0x7fffu + ((v.u >> 16) & 1u);
    return (unsigned short)(r >> 16);
}

// ---------------- CSR build ----------------
__global__ void k_count(const int* __restrict__ edges, int* __restrict__ cnt) {
    int e = blockIdx.x * blockDim.x + threadIdx.x;
    if (e >= NE) return;
    atomicAdd(&cnt[edges[e]], 1);
}

__global__ void k_scan(const int* __restrict__ cnt, int* __restrict__ off,
                       int* __restrict__ cursor) {
    __shared__ int part[1024];
    const int PER = (NN + 1023) / 1024;
    int t = threadIdx.x;
    int base = t * PER;
    int s = 0;
    for (int i = 0; i < PER; i++) {
        int idx = base + i;
        if (idx < NN) s += cnt[idx];
    }
    part[t] = s;
    __syncthreads();
    for (int d = 1; d < 1024; d <<= 1) {
        int tmp = (t >= d) ? part[t - d] : 0;
        __syncthreads();
        part[t] += tmp;
        __syncthreads();
    }
    int run = (t == 0) ? 0 : part[t - 1];
    for (int i = 0; i < PER; i++) {
        int idx = base + i;
        if (idx < NN) {
            off[idx] = run;
            cursor[idx] = run;
            run += cnt[idx];
        }
    }
    if (t == 1023) off[NN] = part[1023];
}

__global__ void k_scatter(const int* __restrict__ edges, int* __restrict__ cursor,
                          int* __restrict__ sorted) {
    int e = blockIdx.x * blockDim.x + threadIdx.x;
    if (e >= NE) return;
    int r = edges[e];
    int p = atomicAdd(&cursor[r], 1);
    sorted[p] = e;
}

// ---------------- weight fragment prepack (bf16, MFMA B-layout) ----------------
// flat idx q = ((n*2+kc)*64 + lane)*8 + j ; value = W[k][c], k=kc*32+(lane>>4)*8+j, c=n*16+(lane&15)
__global__ void k_prepack(const float* __restrict__ e_w2, const float* __restrict__ c_w1,
                          unsigned short* __restrict__ w2f, unsigned short* __restrict__ w1f) {
    int t = blockIdx.x * blockDim.x + threadIdx.x;
    if (t >= 8192) return;
    const float* src = (t < 4096) ? e_w2 : c_w1;
    unsigned short* dst = (t < 4096) ? w2f : w1f;
    int q = t & 4095;
    int j = q & 7, lane = (q >> 3) & 63, kc = (q >> 9) & 1, n = q >> 10;
    int k = kc * 32 + (lane >> 4) * 8 + j;
    int c = n * 16 + (lane & 15);
    dst[q] = f2bf(src[k * H + c]);
}

// ---------------- h = his @ emb_w + emb_b ----------------
__global__ void k_embed(const float* __restrict__ his, const float* __restrict__ w,
                        const float* __restrict__ b, float* __restrict__ h) {
    int t = blockIdx.x * blockDim.x + threadIdx.x;
    if (t >= NN * H) return;
    int n = t >> 6, j = t & 63;
    float acc = b[j];
#pragma unroll
    for (int i = 0; i < 16; i++) acc = fmaf(his[n * 16 + i], w[i * H + j], acc);
    h[t] = acc;
}

// ---------------- per-node precompute: pre_a = h@Wa, pre_b = h@Wb, vel_scale ----------------
__global__ void k_node_pre(const float* __restrict__ h, const float* __restrict__ e_w1,
                           const float* __restrict__ v_w1, const float* __restrict__ v_b1,
                           const float* __restrict__ v_w2, const float* __restrict__ v_b2,
                           float* __restrict__ pre_a, float* __restrict__ pre_b,
                           float* __restrict__ vel) {
    int t = blockIdx.x * blockDim.x + threadIdx.x;
    int n = t >> 6, j = t & 63;
    if (n >= NN) return;
    n = __builtin_amdgcn_readfirstlane(n);
    float a = 0.f, b = 0.f, c = v_b1[j];
#pragma unroll
    for (int i = 0; i < H; i++) {
        float hi = h[n * H + i];
        a = fmaf(hi, e_w1[i * H + j], a);
        b = fmaf(hi, e_w1[(H + i) * H + j], b);
        c = fmaf(hi, v_w1[i * H + j], c);
    }
    pre_a[n * H + j] = a;
    pre_b[n * H + j] = b;
    float tv = silu_f(c) * v_w2[j];
#pragma unroll
    for (int k = 32; k >= 1; k >>= 1) tv += __shfl_xor(tv, k, 64);
    if (j == 0) vel[n] = tv + v_b2[0];
}

// ---------------- fused MFMA edge kernel: wave per 16-edge tile ----------------
__global__ void __launch_bounds__(256) k_edge_mfma(
    const float* __restrict__ xw, const float* __restrict__ pre_a,
    const float* __restrict__ pre_b, const float* __restrict__ edge_attr,
    const int* __restrict__ edges, const int* __restrict__ sorted,
    const float* __restrict__ e_w1, const float* __restrict__ e_b1,
    const float* __restrict__ e_b2, const float* __restrict__ c_b1,
    const float* __restrict__ c_w2,
    const unsigned short* __restrict__ w2f, const unsigned short* __restrict__ w1f,
    float* __restrict__ m_agg, float* __restrict__ coord_agg) {
    __shared__ float lds_m[4][16 * 68];  // per-wave m tile [edge][ch], row pad 68
    __shared__ float lds_t[4][64];       // per-wave trans [edge][4]
    const int w = threadIdx.x >> 6;
    const int l = threadIdx.x & 63;
    const int el = l & 15;  // edge slot (A-frag row / D col)
    const int g = l >> 4;   // lane group

    // persistent weight fragments (bf16, B-layout): 64 VGPRs
    bf16x8 w2frag[4][2], w1frag[4][2];
    const bf16x8* w2v = (const bf16x8*)w2f;
    const bf16x8* w1v = (const bf16x8*)w1f;
#pragma unroll
    for (int n = 0; n < 4; n++)
#pragma unroll
        for (int kc = 0; kc < 2; kc++) {
            w2frag[n][kc] = w2v[(n * 2 + kc) * 64 + l];
            w1frag[n][kc] = w1v[(n * 2 + kc) * 64 + l];
        }
    float b2r[4], cb1r[4], cw2r[4];
#pragma unroll
    for (int n = 0; n < 4; n++) {
        b2r[n] = e_b2[n * 16 + el];
        cb1r[n] = c_b1[n * 16 + el];
        cw2r[n] = c_w2[n * 16 + el];
    }
    f32x4 zero = {0.f, 0.f, 0.f, 0.f};
    float* lm = lds_m[w];
    float* lt = lds_t[w];

    int wave = blockIdx.x * 4 + w;
    for (int t = wave; t < NT; t += gridDim.x * 4) {
        int base = t * 16;
        int eid = sorted[base + el];
        int row = edges[eid];
        int col = edges[NE + eid];
        float dx = xw[row * 3 + 0] - xw[col * 3 + 0];
        float dy = xw[row * 3 + 1] - xw[col * 3 + 1];
        float dz = xw[row * 3 + 2] - xw[col * 3 + 2];
        float radial = dx * dx + dy * dy + dz * dz;
        float ea0 = edge_attr[(size_t)eid * 2 + 0];
        float ea1 = edge_attr[(size_t)eid * 2 + 1];

        // ---- stage1: m1 in A-frag layout: lane computes ch [kc*32+g*8 .. +8) of edge el
        bf16x8 a1[2];
#pragma unroll
        for (int kc = 0; kc < 2; kc++) {
            int ch0 = kc * 32 + g * 8;
            const float4* par = (const float4*)(pre_a + (size_t)row * H + ch0);
            const float4* pbr = (const float4*)(pre_b + (size_t)col * H + ch0);
            const float4* bbr = (const float4*)(e_b1 + ch0);
            const float4* wrr = (const float4*)(e_w1 + 128 * H + ch0);
            const float4* w0r = (const float4*)(e_w1 + 129 * H + ch0);
            const float4* w1r = (const float4*)(e_w1 + 130 * H + ch0);
            float4 pa0 = par[0], pa1 = par[1], pb0 = pbr[0], pb1 = pbr[1];
            float4 bb0 = bbr[0], bb1 = bbr[1], wr0 = wrr[0], wr1 = wrr[1];
            float4 w00 = w0r[0], w01 = w0r[1], w10 = w1r[0], w11 = w1r[1];
            float pa[8] = {pa0.x, pa0.y, pa0.z, pa0.w, pa1.x, pa1.y, pa1.z, pa1.w};
            float pb[8] = {pb0.x, pb0.y, pb0.z, pb0.w, pb1.x, pb1.y, pb1.z, pb1.w};
            float bb[8] = {bb0.x, bb0.y, bb0.z, bb0.w, bb1.x, bb1.y, bb1.z, bb1.w};
            float wr[8] = {wr0.x, wr0.y, wr0.z, wr0.w, wr1.x, wr1.y, wr1.z, wr1.w};
            float w0[8] = {w00.x, w00.y, w00.z, w00.w, w01.x, w01.y, w01.z, w01.w};
            float w1[8] = {w10.x, w10.y, w10.z, w10.w, w11.x, w11.y, w11.z, w11.w};
#pragma unroll
            for (int j = 0; j < 8; j++) {
                float tt = pa[j] + pb[j] + bb[j];
                tt = fmaf(radial, wr[j], tt);
                tt = fmaf(ea0, w0[j], tt);
                tt = fmaf(ea1, w1[j], tt);
                a1[kc][j] = (short)f2bf(silu_fast(tt));
            }
        }

        // ---- stage2: d2[n] = m1 @ W2 (n-th 16-col tile), K=64 in 2 chunks
        f32x4 d2[4];
#pragma unroll
        for (int n = 0; n < 4; n++) {
            d2[n] = __builtin_amdgcn_mfma_f32_16x16x32_bf16(a1[0], w2frag[n][0], zero, 0, 0, 0);
            d2[n] = __builtin_amdgcn_mfma_f32_16x16x32_bf16(a1[1], w2frag[n][1], d2[n], 0, 0, 0);
        }
        // epilogue: m = silu(d2 + b2) -> LDS [edge][ch] (D: row=g*4+r, col=n*16+el)
#pragma unroll
        for (int n = 0; n < 4; n++)
#pragma unroll
            for (int r = 0; r < 4; r++)
                lm[(g * 4 + r) * 68 + n * 16 + el] = silu_fast(d2[n][r] + b2r[n]);
        asm volatile("s_waitcnt lgkmcnt(0)" ::: "memory");

        // ---- stage3: read m back in A-frag layout, c1 = silu(m @ W1c + cb1)
        bf16x8 a3[2];
#pragma unroll
        for (int kc = 0; kc < 2; kc++) {
            const float4* q = (const float4*)(lm + el * 68 + kc * 32 + g * 8);
            float4 q0 = q[0], q1 = q[1];
            float qq[8] = {q0.x, q0.y, q0.z, q0.w, q1.x, q1.y, q1.z, q1.w};
#pragma unroll
            for (int j = 0; j < 8; j++) a3[kc][j] = (short)f2bf(qq[j]);
        }
        f32x4 d3[4];
#pragma unroll
        for (int n = 0; n < 4; n++) {
            d3[n] = __builtin_amdgcn_mfma_f32_16x16x32_bf16(a3[0], w1frag[n][0], zero, 0, 0, 0);
            d3[n] = __builtin_amdgcn_mfma_f32_16x16x32_bf16(a3[1], w1frag[n][1], d3[n], 0, 0, 0);
        }
        // ---- stage4: s_e = sum_ch silu(c1) * c_w2 ; trans = diff * s -> LDS
        float p[4];
#pragma unroll
        for (int r = 0; r < 4; r++) {
            float pp = 0.f;
#pragma unroll
            for (int n = 0; n < 4; n++) pp = fmaf(silu_fast(d3[n][r] + cb1r[n]), cw2r[n], pp);
#pragma unroll
            for (int mk = 1; mk <= 8; mk <<= 1) pp += __shfl_xor(pp, mk, 64);
            p[r] = pp;  // s of edge g*4+r (replicated in 16-group)
        }
#pragma unroll
        for (int r = 0; r < 4; r++) {
            int ep = g * 4 + r;
            float tx = __shfl(dx, ep, 64) * p[r];
            float ty = __shfl(dy, ep, 64) * p[r];
            float tz = __shfl(dz, ep, 64) * p[r];
            if (el < 3) lt[ep * 4 + el] = (el == 0) ? tx : ((el == 1) ? ty : tz);
        }
        asm volatile("s_waitcnt lgkmcnt(0)" ::: "memory");

        // ---- segmented aggregation over sorted rows: lane = channel
        float acc = 0.f, tacc = 0.f;
        int prev = __shfl(row, 0, 64);
#pragma unroll
        for (int e = 0; e < 16; e++) {
            int re = __shfl(row, e, 64);
            if (re != prev) {
                atomicAdd(&m_agg[(size_t)prev * H + l], acc);
                if (l < 3) atomicAdd(&coord_agg[prev * 3 + l], tacc);
                acc = 0.f;
                tacc = 0.f;
                prev = re;
            }
            acc += lm[e * 68 + l];
            if (l < 3) tacc += lt[e * 4 + l];
        }
        atomicAdd(&m_agg[(size_t)prev * H + l], acc);
        if (l < 3) atomicAdd(&coord_agg[prev * 3 + l], tacc);
    }
}

// ---------------- per-node update: v, x, node MLP, h (in-place) ----------------
__global__ void k_node_post(float* __restrict__ h, const float* __restrict__ m_agg,
                            const float* __restrict__ coord_agg, const int* __restrict__ off,
                            const float* __restrict__ vel,
                            const float* __restrict__ n_w1, const float* __restrict__ n_b1,
                            const float* __restrict__ n_w2, const float* __restrict__ n_b2,
                            float* __restrict__ xw, float* __restrict__ vw) {
    int t = blockIdx.x * blockDim.x + threadIdx.x;
    int n = t >> 6, j = t & 63;
    if (n >= NN) return;
    n = __builtin_amdgcn_readfirstlane(n);
    float acc = n_b1[j];
#pragma unroll
    for (int i = 0; i < H; i++) acc = fmaf(h[n * H + i], n_w1[i * H + j], acc);
#pragma unroll
    for (int i = 0; i < H; i++) acc = fmaf(m_agg[n * H + i], n_w1[(H + i) * H + j], acc);
    float tj = silu_f(acc);
    float upd = n_b2[j];
#pragma unroll
    for (int i = 0; i < H; i++) upd = fmaf(__shfl(tj, i, 64), n_w2[i * H + j], upd);
    float hj = h[n * H + j];
    h[n * H + j] = 2.f * hj + upd;
    if (j < 3) {
        float deg = fmaxf((float)(off[n + 1] - off[n]), 1.0f);
        float vv = vw[n * 3 + j];
        vv = vv + coord_agg[n * 3 + j] / deg + vel[n] * vv;
        vw[n * 3 + j] = vv;
        xw[n * 3 + j] += vv;
    }
}

// ---------------- pack outputs: x | h | v ----------------
__global__ void k_pack(const float* __restrict__ xw, const float* __restrict__ h,
                       const float* __restrict__ vw, float* __restrict__ out) {
    int t = blockIdx.x * blockDim.x + threadIdx.x;
    if (t >= NN * 70) return;
    if (t < NN * 3) out[t] = xw[t];
    else if (t < NN * 3 + NN * H) out[t] = h[t - NN * 3];
    else out[t] = vw[t - (NN * 3 + NN * H)];
}

extern "C" void kernel_launch(void* const* d_in, const int* in_sizes, int n_in,
                              void* d_out, int out_size, void* d_ws, size_t ws_size,
                              hipStream_t stream) {
    const float* his       = (const float*)d_in[0];
    const float* x         = (const float*)d_in[1];
    const float* v         = (const float*)d_in[2];
    const float* edge_attr = (const float*)d_in[3];
    const int*   edges     = (const int*)d_in[4];
    const float* emb_w = (const float*)d_in[5];
    const float* emb_b = (const float*)d_in[6];
    const float* e_w1  = (const float*)d_in[7];
    const float* e_b1  = (const float*)d_in[8];
    const float* e_w2  = (const float*)d_in[9];
    const float* e_b2  = (const float*)d_in[10];
    const float* c_w1  = (const float*)d_in[11];
    const float* c_b1  = (const float*)d_in[12];
    const float* c_w2  = (const float*)d_in[13];
    const float* n_w1  = (const float*)d_in[14];
    const float* n_b1  = (const float*)d_in[15];
    const float* n_w2  = (const float*)d_in[16];
    const float* n_b2  = (const float*)d_in[17];
    const float* v_w1  = (const float*)d_in[18];
    const float* v_b1  = (const float*)d_in[19];
    const float* v_w2  = (const float*)d_in[20];
    const float* v_b2  = (const float*)d_in[21];

    char* wsb = (char*)d_ws;
    unsigned short* w2f = (unsigned short*)wsb; wsb += 8192;  // 4096 bf16 padded
    unsigned short* w1f = (unsigned short*)wsb; wsb += 8192;
    float* xw        = (float*)wsb; wsb += (size_t)NN * 3 * 4;
    float* vw        = (float*)wsb; wsb += (size_t)NN * 3 * 4;
    float* h         = (float*)wsb; wsb += (size_t)NN * H * 4;
    float* pre_a     = (float*)wsb; wsb += (size_t)NN * H * 4;
    float* pre_b     = (float*)wsb; wsb += (size_t)NN * H * 4;
    float* vel       = (float*)wsb; wsb += (size_t)NN * 4;
    float* m_agg     = (float*)wsb; wsb += (size_t)NN * H * 4;
    float* coord_agg = (float*)wsb; wsb += (size_t)NN * 3 * 4;
    int* cnt         = (int*)wsb;   wsb += (size_t)NN * 4;
    int* off         = (int*)wsb;   wsb += (size_t)(NN + 4) * 4;
    int* cursor      = (int*)wsb;   wsb += (size_t)NN * 4;
    int* sorted      = (int*)wsb;   wsb += (size_t)NE * 4;

    // CSR build (per call)
    hipMemsetAsync(cnt, 0, (size_t)NN * 4, stream);
    k_count<<<(NE + 255) / 256, 256, 0, stream>>>(edges, cnt);
    k_scan<<<1, 1024, 0, stream>>>(cnt, off, cursor);
    k_scatter<<<(NE + 255) / 256, 256, 0, stream>>>(edges, cursor, sorted);

    k_prepack<<<32, 256, 0, stream>>>(e_w2, c_w1, w2f, w1f);
    hipMemcpyAsync(xw, x, (size_t)NN * 3 * 4, hipMemcpyDeviceToDevice, stream);
    hipMemcpyAsync(vw, v, (size_t)NN * 3 * 4, hipMemcpyDeviceToDevice, stream);
    k_embed<<<(NN * H + 255) / 256, 256, 0, stream>>>(his, emb_w, emb_b, h);

    for (int layer = 0; layer < 3; layer++) {
        hipMemsetAsync(m_agg, 0, (size_t)NN * H * 4, stream);
        hipMemsetAsync(coord_agg, 0, (size_t)NN * 3 * 4, stream);
        k_node_pre<<<(NN * H + 255) / 256, 256, 0, stream>>>(
            h, e_w1, v_w1, v_b1, v_w2, v_b2, pre_a, pre_b, vel);
        k_edge_mfma<<<512, 256, 0, stream>>>(
            xw, pre_a, pre_b, edge_attr, edges, sorted,
            e_w1, e_b1, e_b2, c_b1, c_w2, w2f, w1f, m_agg, coord_agg);
        k_node_post<<<(NN * H + 255) / 256, 256, 0, stream>>>(
            h, m_agg, coord_agg, off, vel, n_w1, n_b1, n_w2, n_b2, xw, vw);
    }
    k_pack<<<(NN * 70 + 255) / 256, 256, 0, stream>>>(xw, h, vw, (float*)d_out);
}

// Round 4
// 1623.805 us; speedup vs baseline: 12.7755x; 2.2992x over previous
//
#include <hip/hip_runtime.h>

#define NN 50000
#define NE 1600000
#define H 64
#define NT (NE / 16)

typedef short bf16x8 __attribute__((ext_vector_type(8)));
typedef float f32x4 __attribute__((ext_vector_type(4)));

__device__ __forceinline__ float silu_f(float x) {
    return x / (1.0f + __expf(-x));
}
__device__ __forceinline__ float silu_fast(float x) {
    return x * __builtin_amdgcn_rcpf(1.0f + __expf(-x));
}
__device__ __forceinline__ unsigned short f2bf(float f) {
    union { float f; unsigned u; } v; v.f = f;
    unsigned r = v.u + 0x7fffu + ((v.u >> 16) & 1u);
    return (unsigned short)(r >> 16);
}

// ---------------- CSR build ----------------
__global__ void k_count(const int* __restrict__ edges, int* __restrict__ cnt) {
    int e = blockIdx.x * blockDim.x + threadIdx.x;
    if (e >= NE) return;
    atomicAdd(&cnt[edges[e]], 1);
}

__global__ void k_scan(const int* __restrict__ cnt, int* __restrict__ off,
                       int* __restrict__ cursor) {
    __shared__ int part[1024];
    const int PER = (NN + 1023) / 1024;
    int t = threadIdx.x;
    int base = t * PER;
    int s = 0;
    for (int i = 0; i < PER; i++) {
        int idx = base + i;
        if (idx < NN) s += cnt[idx];
    }
    part[t] = s;
    __syncthreads();
    for (int d = 1; d < 1024; d <<= 1) {
        int tmp = (t >= d) ? part[t - d] : 0;
        __syncthreads();
        part[t] += tmp;
        __syncthreads();
    }
    int run = (t == 0) ? 0 : part[t - 1];
    for (int i = 0; i < PER; i++) {
        int idx = base + i;
        if (idx < NN) {
            off[idx] = run;
            cursor[idx] = run;
            run += cnt[idx];
        }
    }
    if (t == 1023) off[NN] = part[1023];
}

__global__ void k_scatter(const int* __restrict__ edges, int* __restrict__ cursor,
                          int* __restrict__ sorted) {
    int e = blockIdx.x * blockDim.x + threadIdx.x;
    if (e >= NE) return;
    int r = edges[e];
    int p = atomicAdd(&cursor[r], 1);
    sorted[p] = e;
}

// gather edge data into sorted order (once per call)
__global__ void k_gather(const int* __restrict__ sorted, const int* __restrict__ edges,
                         const float* __restrict__ edge_attr,
                         int* __restrict__ rows_s, int* __restrict__ cols_s,
                         float2* __restrict__ ea_s) {
    int k = blockIdx.x * blockDim.x + threadIdx.x;
    if (k >= NE) return;
    int eid = sorted[k];
    rows_s[k] = edges[eid];
    cols_s[k] = edges[NE + eid];
    ea_s[k] = make_float2(edge_attr[(size_t)eid * 2], edge_attr[(size_t)eid * 2 + 1]);
}

// ---------------- weight fragment prepack (bf16, MFMA B-layout) ----------------
__global__ void k_prepack(const float* __restrict__ e_w2, const float* __restrict__ c_w1,
                          unsigned short* __restrict__ w2f, unsigned short* __restrict__ w1f) {
    int t = blockIdx.x * blockDim.x + threadIdx.x;
    if (t >= 8192) return;
    const float* src = (t < 4096) ? e_w2 : c_w1;
    unsigned short* dst = (t < 4096) ? w2f : w1f;
    int q = t & 4095;
    int j = q & 7, lane = (q >> 3) & 63, kc = (q >> 9) & 1, n = q >> 10;
    int k = kc * 32 + (lane >> 4) * 8 + j;
    int c = n * 16 + (lane & 15);
    dst[q] = f2bf(src[k * H + c]);
}

// ---------------- h = his @ emb_w + emb_b (LDS-staged weights) ----------------
__global__ void __launch_bounds__(256) k_embed(
    const float* __restrict__ his, const float* __restrict__ w,
    const float* __restrict__ b, float* __restrict__ h) {
    __shared__ float lw[16 * 64];
    __shared__ float hs[4][16];
    for (int q = threadIdx.x; q < 16 * 64; q += 256) lw[q] = w[q];
    __syncthreads();
    int wv = threadIdx.x >> 6, j = threadIdx.x & 63;
    float bj = b[j];
    for (int n = blockIdx.x * 4 + wv; n < NN; n += gridDim.x * 4) {
        if (j < 16) hs[wv][j] = his[n * 16 + j];
        float acc = bj;
#pragma unroll
        for (int i = 0; i < 16; i++) acc = fmaf(hs[wv][i], lw[i * 64 + j], acc);
        h[(size_t)n * H + j] = acc;
    }
}

// ---------------- per-node precompute (LDS-staged weights) ----------------
__global__ void __launch_bounds__(256) k_node_pre(
    const float* __restrict__ h, const float* __restrict__ e_w1,
    const float* __restrict__ v_w1, const float* __restrict__ v_b1,
    const float* __restrict__ v_w2, const float* __restrict__ v_b2,
    float* __restrict__ pre_a, float* __restrict__ pre_b,
    float* __restrict__ vel) {
    __shared__ float wa[64 * 64];  // e_w1 rows 0..63
    __shared__ float wb[64 * 64];  // e_w1 rows 64..127
    __shared__ float wv[64 * 64];  // v_w1
    __shared__ float hs[4][64];
    for (int q = threadIdx.x; q < 4096; q += 256) {
        wa[q] = e_w1[q];
        wb[q] = e_w1[4096 + q];
        wv[q] = v_w1[q];
    }
    __syncthreads();
    int w = threadIdx.x >> 6, j = threadIdx.x & 63;
    float vb1j = v_b1[j], vw2j = v_w2[j], vb2 = v_b2[0];
    for (int n = blockIdx.x * 4 + w; n < NN; n += gridDim.x * 4) {
        float hj = h[(size_t)n * H + j];
        hs[w][j] = hj;
        float a = 0.f, b = 0.f, c = vb1j;
#pragma unroll 8
        for (int i = 0; i < 64; i++) {
            float hi = hs[w][i];
            a = fmaf(hi, wa[i * 64 + j], a);
            b = fmaf(hi, wb[i * 64 + j], b);
            c = fmaf(hi, wv[i * 64 + j], c);
        }
        pre_a[(size_t)n * H + j] = a;
        pre_b[(size_t)n * H + j] = b;
        float tv = silu_f(c) * vw2j;
#pragma unroll
        for (int k = 32; k >= 1; k >>= 1) tv += __shfl_xor(tv, k, 64);
        if (j == 0) vel[n] = tv + vb2;
    }
}

// ---------------- fused MFMA edge kernel: wave per 16-edge tile ----------------
__global__ void __launch_bounds__(256) k_edge_mfma(
    const float* __restrict__ xw, const float* __restrict__ pre_a,
    const float* __restrict__ pre_b, const float2* __restrict__ ea_s,
    const int* __restrict__ rows_s, const int* __restrict__ cols_s,
    const float* __restrict__ e_w1, const float* __restrict__ e_b1,
    const float* __restrict__ e_b2, const float* __restrict__ c_b1,
    const float* __restrict__ c_w2,
    const unsigned short* __restrict__ w2f, const unsigned short* __restrict__ w1f,
    float* __restrict__ m_agg, float* __restrict__ coord_agg) {
    __shared__ float lds_m[4][16 * 68];
    __shared__ float lds_t[4][64];
    const int w = threadIdx.x >> 6;
    const int l = threadIdx.x & 63;
    const int el = l & 15;
    const int g = l >> 4;

    bf16x8 w2frag[4][2], w1frag[4][2];
    const bf16x8* w2v = (const bf16x8*)w2f;
    const bf16x8* w1v = (const bf16x8*)w1f;
#pragma unroll
    for (int n = 0; n < 4; n++)
#pragma unroll
        for (int kc = 0; kc < 2; kc++) {
            w2frag[n][kc] = w2v[(n * 2 + kc) * 64 + l];
            w1frag[n][kc] = w1v[(n * 2 + kc) * 64 + l];
        }
    float b2r[4], cb1r[4], cw2r[4];
#pragma unroll
    for (int n = 0; n < 4; n++) {
        b2r[n] = e_b2[n * 16 + el];
        cb1r[n] = c_b1[n * 16 + el];
        cw2r[n] = c_w2[n * 16 + el];
    }
    f32x4 zero = {0.f, 0.f, 0.f, 0.f};
    float* lm = lds_m[w];
    float* lt = lds_t[w];

    int wave = blockIdx.x * 4 + w;
    for (int t = wave; t < NT; t += gridDim.x * 4) {
        int base = t * 16;
        int row = rows_s[base + el];
        int col = cols_s[base + el];
        float2 ea = ea_s[base + el];
        float dx = xw[row * 3 + 0] - xw[col * 3 + 0];
        float dy = xw[row * 3 + 1] - xw[col * 3 + 1];
        float dz = xw[row * 3 + 2] - xw[col * 3 + 2];
        float radial = dx * dx + dy * dy + dz * dz;

        bf16x8 a1[2];
#pragma unroll
        for (int kc = 0; kc < 2; kc++) {
            int ch0 = kc * 32 + g * 8;
            const float4* par = (const float4*)(pre_a + (size_t)row * H + ch0);
            const float4* pbr = (const float4*)(pre_b + (size_t)col * H + ch0);
            const float4* bbr = (const float4*)(e_b1 + ch0);
            const float4* wrr = (const float4*)(e_w1 + 128 * H + ch0);
            const float4* w0r = (const float4*)(e_w1 + 129 * H + ch0);
            const float4* w1r = (const float4*)(e_w1 + 130 * H + ch0);
            float4 pa0 = par[0], pa1 = par[1], pb0 = pbr[0], pb1 = pbr[1];
            float4 bb0 = bbr[0], bb1 = bbr[1], wr0 = wrr[0], wr1 = wrr[1];
            float4 w00 = w0r[0], w01 = w0r[1], w10 = w1r[0], w11 = w1r[1];
            float pa[8] = {pa0.x, pa0.y, pa0.z, pa0.w, pa1.x, pa1.y, pa1.z, pa1.w};
            float pb[8] = {pb0.x, pb0.y, pb0.z, pb0.w, pb1.x, pb1.y, pb1.z, pb1.w};
            float bb[8] = {bb0.x, bb0.y, bb0.z, bb0.w, bb1.x, bb1.y, bb1.z, bb1.w};
            float wr[8] = {wr0.x, wr0.y, wr0.z, wr0.w, wr1.x, wr1.y, wr1.z, wr1.w};
            float w0[8] = {w00.x, w00.y, w00.z, w00.w, w01.x, w01.y, w01.z, w01.w};
            float w1[8] = {w10.x, w10.y, w10.z, w10.w, w11.x, w11.y, w11.z, w11.w};
#pragma unroll
            for (int j = 0; j < 8; j++) {
                float tt = pa[j] + pb[j] + bb[j];
                tt = fmaf(radial, wr[j], tt);
                tt = fmaf(ea.x, w0[j], tt);
                tt = fmaf(ea.y, w1[j], tt);
                a1[kc][j] = (short)f2bf(silu_fast(tt));
            }
        }

        f32x4 d2[4];
#pragma unroll
        for (int n = 0; n < 4; n++) {
            d2[n] = __builtin_amdgcn_mfma_f32_16x16x32_bf16(a1[0], w2frag[n][0], zero, 0, 0, 0);
            d2[n] = __builtin_amdgcn_mfma_f32_16x16x32_bf16(a1[1], w2frag[n][1], d2[n], 0, 0, 0);
        }
#pragma unroll
        for (int n = 0; n < 4; n++)
#pragma unroll
            for (int r = 0; r < 4; r++)
                lm[(g * 4 + r) * 68 + n * 16 + el] = silu_fast(d2[n][r] + b2r[n]);
        asm volatile("s_waitcnt lgkmcnt(0)" ::: "memory");

        bf16x8 a3[2];
#pragma unroll
        for (int kc = 0; kc < 2; kc++) {
            const float4* q = (const float4*)(lm + el * 68 + kc * 32 + g * 8);
            float4 q0 = q[0], q1 = q[1];
            float qq[8] = {q0.x, q0.y, q0.z, q0.w, q1.x, q1.y, q1.z, q1.w};
#pragma unroll
            for (int j = 0; j < 8; j++) a3[kc][j] = (short)f2bf(qq[j]);
        }
        f32x4 d3[4];
#pragma unroll
        for (int n = 0; n < 4; n++) {
            d3[n] = __builtin_amdgcn_mfma_f32_16x16x32_bf16(a3[0], w1frag[n][0], zero, 0, 0, 0);
            d3[n] = __builtin_amdgcn_mfma_f32_16x16x32_bf16(a3[1], w1frag[n][1], d3[n], 0, 0, 0);
        }
        float p[4];
#pragma unroll
        for (int r = 0; r < 4; r++) {
            float pp = 0.f;
#pragma unroll
            for (int n = 0; n < 4; n++) pp = fmaf(silu_fast(d3[n][r] + cb1r[n]), cw2r[n], pp);
#pragma unroll
            for (int mk = 1; mk <= 8; mk <<= 1) pp += __shfl_xor(pp, mk, 64);
            p[r] = pp;
        }
#pragma unroll
        for (int r = 0; r < 4; r++) {
            int ep = g * 4 + r;
            float tx = __shfl(dx, ep, 64) * p[r];
            float ty = __shfl(dy, ep, 64) * p[r];
            float tz = __shfl(dz, ep, 64) * p[r];
            if (el < 3) lt[ep * 4 + el] = (el == 0) ? tx : ((el == 1) ? ty : tz);
        }
        asm volatile("s_waitcnt lgkmcnt(0)" ::: "memory");

        float acc = 0.f, tacc = 0.f;
        int prev = __shfl(row, 0, 64);
#pragma unroll
        for (int e = 0; e < 16; e++) {
            int re = __shfl(row, e, 64);
            if (re != prev) {
                atomicAdd(&m_agg[(size_t)prev * H + l], acc);
                if (l < 3) atomicAdd(&coord_agg[prev * 3 + l], tacc);
                acc = 0.f;
                tacc = 0.f;
                prev = re;
            }
            acc += lm[e * 68 + l];
            if (l < 3) tacc += lt[e * 4 + l];
        }
        atomicAdd(&m_agg[(size_t)prev * H + l], acc);
        if (l < 3) atomicAdd(&coord_agg[prev * 3 + l], tacc);
    }
}

// ---------------- per-node update (LDS-staged weights) ----------------
__global__ void __launch_bounds__(256) k_node_post(
    float* __restrict__ h, const float* __restrict__ m_agg,
    const float* __restrict__ coord_agg, const int* __restrict__ off,
    const float* __restrict__ vel,
    const float* __restrict__ n_w1, const float* __restrict__ n_b1,
    const float* __restrict__ n_w2, const float* __restrict__ n_b2,
    float* __restrict__ xw, float* __restrict__ vw) {
    __shared__ float w1[128 * 64];  // 32 KB
    __shared__ float w2[64 * 64];   // 16 KB
    __shared__ float st[4][192];
    for (int q = threadIdx.x; q < 8192; q += 256) w1[q] = n_w1[q];
    for (int q = threadIdx.x; q < 4096; q += 256) w2[q] = n_w2[q];
    __syncthreads();
    int w = threadIdx.x >> 6, j = threadIdx.x & 63;
    float b1j = n_b1[j], b2j = n_b2[j];
    for (int n = blockIdx.x * 4 + w; n < NN; n += gridDim.x * 4) {
        float hj = h[(size_t)n * H + j];
        float mj = m_agg[(size_t)n * H + j];
        st[w][j] = hj;
        st[w][64 + j] = mj;
        float a0 = b1j, a1 = 0.f;
#pragma unroll 8
        for (int i = 0; i < 64; i++) {
            a0 = fmaf(st[w][i], w1[i * 64 + j], a0);
            a1 = fmaf(st[w][64 + i], w1[(64 + i) * 64 + j], a1);
        }
        float tj = silu_f(a0 + a1);
        st[w][128 + j] = tj;
        float upd = b2j;
#pragma unroll 8
        for (int i = 0; i < 64; i++) upd = fmaf(st[w][128 + i], w2[i * 64 + j], upd);
        h[(size_t)n * H + j] = 2.f * hj + upd;
        if (j < 3) {
            float deg = fmaxf((float)(off[n + 1] - off[n]), 1.0f);
            float vv = vw[n * 3 + j];
            vv = vv + coord_agg[n * 3 + j] / deg + vel[n] * vv;
            vw[n * 3 + j] = vv;
            xw[n * 3 + j] += vv;
        }
    }
}

// ---------------- pack outputs: x | h | v ----------------
__global__ void k_pack(const float* __restrict__ xw, const float* __restrict__ h,
                       const float* __restrict__ vw, float* __restrict__ out) {
    int t = blockIdx.x * blockDim.x + threadIdx.x;
    if (t >= NN * 70) return;
    if (t < NN * 3) out[t] = xw[t];
    else if (t < NN * 3 + NN * H) out[t] = h[t - NN * 3];
    else out[t] = vw[t - (NN * 3 + NN * H)];
}

extern "C" void kernel_launch(void* const* d_in, const int* in_sizes, int n_in,
                              void* d_out, int out_size, void* d_ws, size_t ws_size,
                              hipStream_t stream) {
    const float* his       = (const float*)d_in[0];
    const float* x         = (const float*)d_in[1];
    const float* v         = (const float*)d_in[2];
    const float* edge_attr = (const float*)d_in[3];
    const int*   edges     = (const int*)d_in[4];
    const float* emb_w = (const float*)d_in[5];
    const float* emb_b = (const float*)d_in[6];
    const float* e_w1  = (const float*)d_in[7];
    const float* e_b1  = (const float*)d_in[8];
    const float* e_w2  = (const float*)d_in[9];
    const float* e_b2  = (const float*)d_in[10];
    const float* c_w1  = (const float*)d_in[11];
    const float* c_b1  = (const float*)d_in[12];
    const float* c_w2  = (const float*)d_in[13];
    const float* n_w1  = (const float*)d_in[14];
    const float* n_b1  = (const float*)d_in[15];
    const float* n_w2  = (const float*)d_in[16];
    const float* n_b2  = (const float*)d_in[17];
    const float* v_w1  = (const float*)d_in[18];
    const float* v_b1  = (const float*)d_in[19];
    const float* v_w2  = (const float*)d_in[20];
    const float* v_b2  = (const float*)d_in[21];

    char* wsb = (char*)d_ws;
    unsigned short* w2f = (unsigned short*)wsb; wsb += 8192;
    unsigned short* w1f = (unsigned short*)wsb; wsb += 8192;
    float* xw        = (float*)wsb; wsb += (size_t)NN * 3 * 4;
    float* vw        = (float*)wsb; wsb += (size_t)NN * 3 * 4;
    float* h         = (float*)wsb; wsb += (size_t)NN * H * 4;
    float* pre_a     = (float*)wsb; wsb += (size_t)NN * H * 4;
    float* pre_b     = (float*)wsb; wsb += (size_t)NN * H * 4;
    float* vel       = (float*)wsb; wsb += (size_t)NN * 4;
    float* m_agg     = (float*)wsb; wsb += (size_t)NN * H * 4;
    float* coord_agg = (float*)wsb; wsb += (size_t)NN * 3 * 4;
    int* cnt         = (int*)wsb;   wsb += (size_t)NN * 4;
    int* off         = (int*)wsb;   wsb += (size_t)(NN + 4) * 4;
    int* cursor      = (int*)wsb;   wsb += (size_t)NN * 4;
    int* sorted      = (int*)wsb;   wsb += (size_t)NE * 4;
    int* rows_s      = (int*)wsb;   wsb += (size_t)NE * 4;
    int* cols_s      = (int*)wsb;   wsb += (size_t)NE * 4;
    float2* ea_s     = (float2*)wsb; wsb += (size_t)NE * 8;

    // CSR build (per call)
    hipMemsetAsync(cnt, 0, (size_t)NN * 4, stream);
    k_count<<<(NE + 255) / 256, 256, 0, stream>>>(edges, cnt);
    k_scan<<<1, 1024, 0, stream>>>(cnt, off, cursor);
    k_scatter<<<(NE + 255) / 256, 256, 0, stream>>>(edges, cursor, sorted);
    k_gather<<<(NE + 255) / 256, 256, 0, stream>>>(sorted, edges, edge_attr,
                                                   rows_s, cols_s, ea_s);

    k_prepack<<<32, 256, 0, stream>>>(e_w2, c_w1, w2f, w1f);
    hipMemcpyAsync(xw, x, (size_t)NN * 3 * 4, hipMemcpyDeviceToDevice, stream);
    hipMemcpyAsync(vw, v, (size_t)NN * 3 * 4, hipMemcpyDeviceToDevice, stream);
    k_embed<<<768, 256, 0, stream>>>(his, emb_w, emb_b, h);

    for (int layer = 0; layer < 3; layer++) {
        hipMemsetAsync(m_agg, 0, (size_t)NN * H * 4, stream);
        hipMemsetAsync(coord_agg, 0, (size_t)NN * 3 * 4, stream);
        k_node_pre<<<768, 256, 0, stream>>>(
            h, e_w1, v_w1, v_b1, v_w2, v_b2, pre_a, pre_b, vel);
        k_edge_mfma<<<512, 256, 0, stream>>>(
            xw, pre_a, pre_b, ea_s, rows_s, cols_s,
            e_w1, e_b1, e_b2, c_b1, c_w2, w2f, w1f, m_agg, coord_agg);
        k_node_post<<<768, 256, 0, stream>>>(
            h, m_agg, coord_agg, off, vel, n_w1, n_b1, n_w2, n_b2, xw, vw);
    }
    k_pack<<<(NN * 70 + 255) / 256, 256, 0, stream>>>(xw, h, vw, (float*)d_out);
}

// Round 7
// 1342.833 us; speedup vs baseline: 15.4486x; 1.2092x over previous
//
#include <hip/hip_runtime.h>

#define NN 50000
#define NE 1600000
#define H 64
#define NT (NE / 16)
#define NTILE_N (NN / 16)  // 3125 exact

typedef short bf16x8 __attribute__((ext_vector_type(8)));
typedef float f32x4 __attribute__((ext_vector_type(4)));

__device__ __forceinline__ float silu_f(float x) {
    return x / (1.0f + __expf(-x));
}
__device__ __forceinline__ float silu_fast(float x) {
    return x * __builtin_amdgcn_rcpf(1.0f + __expf(-x));
}
__device__ __forceinline__ unsigned short f2bf(float f) {
    union { float f; unsigned u; } v; v.f = f;
    unsigned r = v.u + 0x7fffu + ((v.u >> 16) & 1u);
    return (unsigned short)(r >> 16);
}

// ---------------- CSR build ----------------
__global__ void k_count(const int* __restrict__ edges, int* __restrict__ cnt) {
    int e = blockIdx.x * blockDim.x + threadIdx.x;
    if (e >= NE) return;
    atomicAdd(&cnt[edges[e]], 1);
}

__global__ void k_scan(const int* __restrict__ cnt, int* __restrict__ off,
                       int* __restrict__ cursor) {
    __shared__ int part[1024];
    const int PER = (NN + 1023) / 1024;
    int t = threadIdx.x;
    int base = t * PER;
    int s = 0;
    for (int i = 0; i < PER; i++) {
        int idx = base + i;
        if (idx < NN) s += cnt[idx];
    }
    part[t] = s;
    __syncthreads();
    for (int d = 1; d < 1024; d <<= 1) {
        int tmp = (t >= d) ? part[t - d] : 0;
        __syncthreads();
        part[t] += tmp;
        __syncthreads();
    }
    int run = (t == 0) ? 0 : part[t - 1];
    for (int i = 0; i < PER; i++) {
        int idx = base + i;
        if (idx < NN) {
            off[idx] = run;
            cursor[idx] = run;
            run += cnt[idx];
        }
    }
    if (t == 1023) off[NN] = part[1023];
}

__global__ void k_scatter(const int* __restrict__ edges, int* __restrict__ cursor,
                          int* __restrict__ sorted) {
    int e = blockIdx.x * blockDim.x + threadIdx.x;
    if (e >= NE) return;
    int r = edges[e];
    int p = atomicAdd(&cursor[r], 1);
    sorted[p] = e;
}

__global__ void k_gather(const int* __restrict__ sorted, const int* __restrict__ edges,
                         const float* __restrict__ edge_attr,
                         int* __restrict__ rows_s, int* __restrict__ cols_s,
                         float2* __restrict__ ea_s) {
    int k = blockIdx.x * blockDim.x + threadIdx.x;
    if (k >= NE) return;
    int eid = sorted[k];
    rows_s[k] = edges[eid];
    cols_s[k] = edges[NE + eid];
    ea_s[k] = make_float2(edge_attr[(size_t)eid * 2], edge_attr[(size_t)eid * 2 + 1]);
}

// ---------------- generic weight prepack: [K][64] f32 -> MFMA B-frags bf16 ----------------
__global__ void k_prepack(const float* __restrict__ src, unsigned short* __restrict__ dst,
                          int K) {
    int t = blockIdx.x * blockDim.x + threadIdx.x;
    if (t >= K * 64) return;
    int j = t & 7, lane = (t >> 3) & 63, f = t >> 9;
    int nkc = K >> 5;
    int kc = f % nkc, n = f / nkc;
    int k = kc * 32 + ((lane >> 4) << 3) + j;
    int c = n * 16 + (lane & 15);
    dst[t] = f2bf(src[k * 64 + c]);
}

// ---------------- h = his @ emb_w + emb_b ----------------
__global__ void __launch_bounds__(256) k_embed(
    const float* __restrict__ his, const float* __restrict__ w,
    const float* __restrict__ b, float* __restrict__ h) {
    __shared__ float lw[16 * 64];
    __shared__ float hs[4][16];
    for (int q = threadIdx.x; q < 16 * 64; q += 256) lw[q] = w[q];
    __syncthreads();
    int wv = threadIdx.x >> 6, j = threadIdx.x & 63;
    float bj = b[j];
    for (int n = blockIdx.x * 4 + wv; n < NN; n += gridDim.x * 4) {
        if (j < 16) hs[wv][j] = his[n * 16 + j];
        float acc = bj;
#pragma unroll
        for (int i = 0; i < 16; i++) acc = fmaf(hs[wv][i], lw[i * 64 + j], acc);
        h[(size_t)n * H + j] = acc;
    }
}

// ---------------- MFMA node-pre: pre_a = h@Wa, pre_b = h@Wb, vel scale ----------------
// D layout: d[n][r] = (node g*4+r, channel n*16+el)
__global__ void __launch_bounds__(256, 1) k_node_pre_mfma(
    const float* __restrict__ h,
    const unsigned short* __restrict__ waf, const unsigned short* __restrict__ wbf,
    const unsigned short* __restrict__ wvf,
    const float* __restrict__ v_b1, const float* __restrict__ v_w2,
    const float* __restrict__ v_b2,
    float* __restrict__ pre_a, float* __restrict__ pre_b, float* __restrict__ vel) {
    const int w = threadIdx.x >> 6, l = threadIdx.x & 63;
    const int el = l & 15, g = l >> 4;

    bf16x8 wa[4][2], wb[4][2], wv[4][2];
    const bf16x8 *pa = (const bf16x8*)waf, *pb = (const bf16x8*)wbf, *pv = (const bf16x8*)wvf;
#pragma unroll
    for (int n = 0; n < 4; n++)
#pragma unroll
        for (int kc = 0; kc < 2; kc++) {
            wa[n][kc] = pa[(n * 2 + kc) * 64 + l];
            wb[n][kc] = pb[(n * 2 + kc) * 64 + l];
            wv[n][kc] = pv[(n * 2 + kc) * 64 + l];
        }
    float vb1r[4], vw2r[4];
#pragma unroll
    for (int n = 0; n < 4; n++) {
        vb1r[n] = v_b1[n * 16 + el];   // bias indexed by channel column
        vw2r[n] = v_w2[n * 16 + el];
    }
    float vb2s = v_b2[0];
    f32x4 zero = {0.f, 0.f, 0.f, 0.f};

    int wave = blockIdx.x * 4 + w;
    for (int t = wave; t < NTILE_N; t += gridDim.x * 4) {
        int base = t * 16;
        bf16x8 a[2];
#pragma unroll
        for (int kc = 0; kc < 2; kc++) {
            const float4* src = (const float4*)(h + (size_t)(base + el) * H + kc * 32 + g * 8);
            float4 q0 = src[0], q1 = src[1];
            float qq[8] = {q0.x, q0.y, q0.z, q0.w, q1.x, q1.y, q1.z, q1.w};
#pragma unroll
            for (int j = 0; j < 8; j++) a[kc][j] = (short)f2bf(qq[j]);
        }
        f32x4 da[4], db[4], dc[4];
#pragma unroll
        for (int n = 0; n < 4; n++) {
            da[n] = __builtin_amdgcn_mfma_f32_16x16x32_bf16(a[0], wa[n][0], zero, 0, 0, 0);
            da[n] = __builtin_amdgcn_mfma_f32_16x16x32_bf16(a[1], wa[n][1], da[n], 0, 0, 0);
            db[n] = __builtin_amdgcn_mfma_f32_16x16x32_bf16(a[0], wb[n][0], zero, 0, 0, 0);
            db[n] = __builtin_amdgcn_mfma_f32_16x16x32_bf16(a[1], wb[n][1], db[n], 0, 0, 0);
            dc[n] = __builtin_amdgcn_mfma_f32_16x16x32_bf16(a[0], wv[n][0], zero, 0, 0, 0);
            dc[n] = __builtin_amdgcn_mfma_f32_16x16x32_bf16(a[1], wv[n][1], dc[n], 0, 0, 0);
        }
        // direct store in correct (node, channel) orientation
#pragma unroll
        for (int n = 0; n < 4; n++)
#pragma unroll
            for (int r = 0; r < 4; r++) {
                pre_a[(size_t)(base + g * 4 + r) * H + n * 16 + el] = da[n][r];
                pre_b[(size_t)(base + g * 4 + r) * H + n * 16 + el] = db[n][r];
            }
        // vel: per-node sum over channels; node g*4+r lives in reg r across the 16 lanes of group g
        float sr[4];
#pragma unroll
        for (int r = 0; r < 4; r++) {
            float s = 0.f;
#pragma unroll
            for (int n = 0; n < 4; n++) s = fmaf(silu_fast(dc[n][r] + vb1r[n]), vw2r[n], s);
#pragma unroll
            for (int mk = 1; mk <= 8; mk <<= 1) s += __shfl_xor(s, mk, 64);
            sr[r] = s;
        }
        if (el == 0) {
#pragma unroll
            for (int r = 0; r < 4; r++) vel[base + g * 4 + r] = sr[r] + vb2s;
        }
    }
}

// ---------------- fused MFMA edge kernel: wave per 16-edge tile ----------------
__global__ void __launch_bounds__(256) k_edge_mfma(
    const float* __restrict__ xw, const float* __restrict__ pre_a,
    const float* __restrict__ pre_b, const float2* __restrict__ ea_s,
    const int* __restrict__ rows_s, const int* __restrict__ cols_s,
    const float* __restrict__ e_w1, const float* __restrict__ e_b1,
    const float* __restrict__ e_b2, const float* __restrict__ c_b1,
    const float* __restrict__ c_w2,
    const unsigned short* __restrict__ w2f, const unsigned short* __restrict__ w1f,
    float* __restrict__ m_agg, float* __restrict__ coord_agg) {
    __shared__ float lds_m[4][16 * 68];
    __shared__ float lds_t[4][64];
    const int w = threadIdx.x >> 6;
    const int l = threadIdx.x & 63;
    const int el = l & 15;
    const int g = l >> 4;

    bf16x8 w2frag[4][2], w1frag[4][2];
    const bf16x8* w2v = (const bf16x8*)w2f;
    const bf16x8* w1v = (const bf16x8*)w1f;
#pragma unroll
    for (int n = 0; n < 4; n++)
#pragma unroll
        for (int kc = 0; kc < 2; kc++) {
            w2frag[n][kc] = w2v[(n * 2 + kc) * 64 + l];
            w1frag[n][kc] = w1v[(n * 2 + kc) * 64 + l];
        }
    float b2r[4], cb1r[4], cw2r[4];
#pragma unroll
    for (int n = 0; n < 4; n++) {
        b2r[n] = e_b2[n * 16 + el];
        cb1r[n] = c_b1[n * 16 + el];
        cw2r[n] = c_w2[n * 16 + el];
    }
    f32x4 zero = {0.f, 0.f, 0.f, 0.f};
    float* lm = lds_m[w];
    float* lt = lds_t[w];

    int wave = blockIdx.x * 4 + w;
    for (int t = wave; t < NT; t += gridDim.x * 4) {
        int base = t * 16;
        int row = rows_s[base + el];
        int col = cols_s[base + el];
        float2 ea = ea_s[base + el];
        float dx = xw[row * 3 + 0] - xw[col * 3 + 0];
        float dy = xw[row * 3 + 1] - xw[col * 3 + 1];
        float dz = xw[row * 3 + 2] - xw[col * 3 + 2];
        float radial = dx * dx + dy * dy + dz * dz;

        bf16x8 a1[2];
#pragma unroll
        for (int kc = 0; kc < 2; kc++) {
            int ch0 = kc * 32 + g * 8;
            const float4* par = (const float4*)(pre_a + (size_t)row * H + ch0);
            const float4* pbr = (const float4*)(pre_b + (size_t)col * H + ch0);
            const float4* bbr = (const float4*)(e_b1 + ch0);
            const float4* wrr = (const float4*)(e_w1 + 128 * H + ch0);
            const float4* w0r = (const float4*)(e_w1 + 129 * H + ch0);
            const float4* w1r = (const float4*)(e_w1 + 130 * H + ch0);
            float4 pa0 = par[0], pa1 = par[1], pb0 = pbr[0], pb1 = pbr[1];
            float4 bb0 = bbr[0], bb1 = bbr[1], wr0 = wrr[0], wr1 = wrr[1];
            float4 w00 = w0r[0], w01 = w0r[1], w10 = w1r[0], w11 = w1r[1];
            float pa[8] = {pa0.x, pa0.y, pa0.z, pa0.w, pa1.x, pa1.y, pa1.z, pa1.w};
            float pb[8] = {pb0.x, pb0.y, pb0.z, pb0.w, pb1.x, pb1.y, pb1.z, pb1.w};
            float bb[8] = {bb0.x, bb0.y, bb0.z, bb0.w, bb1.x, bb1.y, bb1.z, bb1.w};
            float wr[8] = {wr0.x, wr0.y, wr0.z, wr0.w, wr1.x, wr1.y, wr1.z, wr1.w};
            float w0[8] = {w00.x, w00.y, w00.z, w00.w, w01.x, w01.y, w01.z, w01.w};
            float w1[8] = {w10.x, w10.y, w10.z, w10.w, w11.x, w11.y, w11.z, w11.w};
#pragma unroll
            for (int j = 0; j < 8; j++) {
                float tt = pa[j] + pb[j] + bb[j];
                tt = fmaf(radial, wr[j], tt);
                tt = fmaf(ea.x, w0[j], tt);
                tt = fmaf(ea.y, w1[j], tt);
                a1[kc][j] = (short)f2bf(silu_fast(tt));
            }
        }

        f32x4 d2[4];
#pragma unroll
        for (int n = 0; n < 4; n++) {
            d2[n] = __builtin_amdgcn_mfma_f32_16x16x32_bf16(a1[0], w2frag[n][0], zero, 0, 0, 0);
            d2[n] = __builtin_amdgcn_mfma_f32_16x16x32_bf16(a1[1], w2frag[n][1], d2[n], 0, 0, 0);
        }
#pragma unroll
        for (int n = 0; n < 4; n++)
#pragma unroll
            for (int r = 0; r < 4; r++)
                lm[(g * 4 + r) * 68 + n * 16 + el] = silu_fast(d2[n][r] + b2r[n]);
        asm volatile("s_waitcnt lgkmcnt(0)" ::: "memory");

        bf16x8 a3[2];
#pragma unroll
        for (int kc = 0; kc < 2; kc++) {
            const float4* q = (const float4*)(lm + el * 68 + kc * 32 + g * 8);
            float4 q0 = q[0], q1 = q[1];
            float qq[8] = {q0.x, q0.y, q0.z, q0.w, q1.x, q1.y, q1.z, q1.w};
#pragma unroll
            for (int j = 0; j < 8; j++) a3[kc][j] = (short)f2bf(qq[j]);
        }
        f32x4 d3[4];
#pragma unroll
        for (int n = 0; n < 4; n++) {
            d3[n] = __builtin_amdgcn_mfma_f32_16x16x32_bf16(a3[0], w1frag[n][0], zero, 0, 0, 0);
            d3[n] = __builtin_amdgcn_mfma_f32_16x16x32_bf16(a3[1], w1frag[n][1], d3[n], 0, 0, 0);
        }
        float p[4];
#pragma unroll
        for (int r = 0; r < 4; r++) {
            float pp = 0.f;
#pragma unroll
            for (int n = 0; n < 4; n++) pp = fmaf(silu_fast(d3[n][r] + cb1r[n]), cw2r[n], pp);
#pragma unroll
            for (int mk = 1; mk <= 8; mk <<= 1) pp += __shfl_xor(pp, mk, 64);
            p[r] = pp;
        }
#pragma unroll
        for (int r = 0; r < 4; r++) {
            int ep = g * 4 + r;
            float tx = __shfl(dx, ep, 64) * p[r];
            float ty = __shfl(dy, ep, 64) * p[r];
            float tz = __shfl(dz, ep, 64) * p[r];
            if (el < 3) lt[ep * 4 + el] = (el == 0) ? tx : ((el == 1) ? ty : tz);
        }
        asm volatile("s_waitcnt lgkmcnt(0)" ::: "memory");

        float acc = 0.f, tacc = 0.f;
        int prev = __shfl(row, 0, 64);
#pragma unroll
        for (int e = 0; e < 16; e++) {
            int re = __shfl(row, e, 64);
            if (re != prev) {
                atomicAdd(&m_agg[(size_t)prev * H + l], acc);
                if (l < 3) atomicAdd(&coord_agg[prev * 3 + l], tacc);
                acc = 0.f;
                tacc = 0.f;
                prev = re;
            }
            acc += lm[e * 68 + l];
            if (l < 3) tacc += lt[e * 4 + l];
        }
        atomicAdd(&m_agg[(size_t)prev * H + l], acc);
        if (l < 3) atomicAdd(&coord_agg[prev * 3 + l], tacc);
    }
}

// ---------------- MFMA node-post: node MLP + h recurrence + x/v update ----------------
// D layout: d[n][r] = (node g*4+r, channel n*16+el)
__global__ void __launch_bounds__(256, 1) k_node_post_mfma(
    float* __restrict__ h, const float* __restrict__ m_agg,
    const float* __restrict__ coord_agg, const int* __restrict__ off,
    const float* __restrict__ vel,
    const unsigned short* __restrict__ nw1f, const unsigned short* __restrict__ nw2f,
    const float* __restrict__ n_b1, const float* __restrict__ n_b2,
    float* __restrict__ xw, float* __restrict__ vw) {
    __shared__ float st_all[4][16 * 68];  // [node][ch], stride 68 (2-way banks, free)
    const int w = threadIdx.x >> 6, l = threadIdx.x & 63;
    const int el = l & 15, g = l >> 4;
    float* st = st_all[w];

    bf16x8 w1n[4][4], w2n[4][2];
    const bf16x8* p1 = (const bf16x8*)nw1f;
    const bf16x8* p2 = (const bf16x8*)nw2f;
#pragma unroll
    for (int n = 0; n < 4; n++) {
#pragma unroll
        for (int kc = 0; kc < 4; kc++) w1n[n][kc] = p1[(n * 4 + kc) * 64 + l];
#pragma unroll
        for (int kc = 0; kc < 2; kc++) w2n[n][kc] = p2[(n * 2 + kc) * 64 + l];
    }
    float b1r[4], b2r[4];
#pragma unroll
    for (int n = 0; n < 4; n++) {
        b1r[n] = n_b1[n * 16 + el];   // bias indexed by channel column
        b2r[n] = n_b2[n * 16 + el];
    }
    f32x4 zero = {0.f, 0.f, 0.f, 0.f};

    int wave = blockIdx.x * 4 + w;
    for (int t = wave; t < NTILE_N; t += gridDim.x * 4) {
        int base = t * 16;
        bf16x8 a1[4];
#pragma unroll
        for (int kc = 0; kc < 4; kc++) {
            const float* srcp = (kc < 2)
                ? (h + (size_t)(base + el) * H + kc * 32 + g * 8)
                : (m_agg + (size_t)(base + el) * H + (kc - 2) * 32 + g * 8);
            const float4* src = (const float4*)srcp;
            float4 q0 = src[0], q1 = src[1];
            float qq[8] = {q0.x, q0.y, q0.z, q0.w, q1.x, q1.y, q1.z, q1.w};
#pragma unroll
            for (int j = 0; j < 8; j++) a1[kc][j] = (short)f2bf(qq[j]);
        }
        f32x4 d1[4];
#pragma unroll
        for (int n = 0; n < 4; n++) {
            d1[n] = __builtin_amdgcn_mfma_f32_16x16x32_bf16(a1[0], w1n[n][0], zero, 0, 0, 0);
            d1[n] = __builtin_amdgcn_mfma_f32_16x16x32_bf16(a1[1], w1n[n][1], d1[n], 0, 0, 0);
            d1[n] = __builtin_amdgcn_mfma_f32_16x16x32_bf16(a1[2], w1n[n][2], d1[n], 0, 0, 0);
            d1[n] = __builtin_amdgcn_mfma_f32_16x16x32_bf16(a1[3], w1n[n][3], d1[n], 0, 0, 0);
        }
        // tj -> LDS in (node, channel) orientation
#pragma unroll
        for (int n = 0; n < 4; n++)
#pragma unroll
            for (int r = 0; r < 4; r++)
                st[(g * 4 + r) * 68 + n * 16 + el] = silu_fast(d1[n][r] + b1r[n]);
        asm volatile("s_waitcnt lgkmcnt(0)" ::: "memory");

        bf16x8 a2[2];
#pragma unroll
        for (int kc = 0; kc < 2; kc++) {
            const float4* q = (const float4*)(st + el * 68 + kc * 32 + g * 8);
            float4 q0 = q[0], q1 = q[1];
            float qq[8] = {q0.x, q0.y, q0.z, q0.w, q1.x, q1.y, q1.z, q1.w};
#pragma unroll
            for (int j = 0; j < 8; j++) a2[kc][j] = (short)f2bf(qq[j]);
        }
        f32x4 d2[4];
#pragma unroll
        for (int n = 0; n < 4; n++) {
            d2[n] = __builtin_amdgcn_mfma_f32_16x16x32_bf16(a2[0], w2n[n][0], zero, 0, 0, 0);
            d2[n] = __builtin_amdgcn_mfma_f32_16x16x32_bf16(a2[1], w2n[n][1], d2[n], 0, 0, 0);
        }
#pragma unroll
        for (int n = 0; n < 4; n++)
#pragma unroll
            for (int r = 0; r < 4; r++)
                st[(g * 4 + r) * 68 + n * 16 + el] = d2[n][r] + b2r[n];
        asm volatile("s_waitcnt lgkmcnt(0)" ::: "memory");
#pragma unroll
        for (int e = 0; e < 16; e++) {
            size_t idx = (size_t)(base + e) * H + l;
            h[idx] = 2.f * h[idx] + st[e * 68 + l];
        }
        if (l < 48) {
            int c = l >> 4;
            int node = base + el;
            float deg = fmaxf((float)(off[node + 1] - off[node]), 1.0f);
            float vv = vw[node * 3 + c];
            vv = vv + coord_agg[node * 3 + c] / deg + vel[node] * vv;
            vw[node * 3 + c] = vv;
            xw[node * 3 + c] += vv;
        }
    }
}

// ---------------- pack outputs: x | h | v ----------------
__global__ void k_pack(const float* __restrict__ xw, const float* __restrict__ h,
                       const float* __restrict__ vw, float* __restrict__ out) {
    int t = blockIdx.x * blockDim.x + threadIdx.x;
    if (t >= NN * 70) return;
    if (t < NN * 3) out[t] = xw[t];
    else if (t < NN * 3 + NN * H) out[t] = h[t - NN * 3];
    else out[t] = vw[t - (NN * 3 + NN * H)];
}

extern "C" void kernel_launch(void* const* d_in, const int* in_sizes, int n_in,
                              void* d_out, int out_size, void* d_ws, size_t ws_size,
                              hipStream_t stream) {
    const float* his       = (const float*)d_in[0];
    const float* x         = (const float*)d_in[1];
    const float* v         = (const float*)d_in[2];
    const float* edge_attr = (const float*)d_in[3];
    const int*   edges     = (const int*)d_in[4];
    const float* emb_w = (const float*)d_in[5];
    const float* emb_b = (const float*)d_in[6];
    const float* e_w1  = (const float*)d_in[7];
    const float* e_b1  = (const float*)d_in[8];
    const float* e_w2  = (const float*)d_in[9];
    const float* e_b2  = (const float*)d_in[10];
    const float* c_w1  = (const float*)d_in[11];
    const float* c_b1  = (const float*)d_in[12];
    const float* c_w2  = (const float*)d_in[13];
    const float* n_w1  = (const float*)d_in[14];
    const float* n_b1  = (const float*)d_in[15];
    const float* n_w2  = (const float*)d_in[16];
    const float* n_b2  = (const float*)d_in[17];
    const float* v_w1  = (const float*)d_in[18];
    const float* v_b1  = (const float*)d_in[19];
    const float* v_w2  = (const float*)d_in[20];
    const float* v_b2  = (const float*)d_in[21];

    char* wsb = (char*)d_ws;
    unsigned short* w2f  = (unsigned short*)wsb; wsb += 8192;
    unsigned short* w1f  = (unsigned short*)wsb; wsb += 8192;
    unsigned short* waf  = (unsigned short*)wsb; wsb += 8192;
    unsigned short* wbf  = (unsigned short*)wsb; wsb += 8192;
    unsigned short* wvf  = (unsigned short*)wsb; wsb += 8192;
    unsigned short* nw1f = (unsigned short*)wsb; wsb += 16384;
    unsigned short* nw2f = (unsigned short*)wsb; wsb += 8192;
    float* xw        = (float*)wsb; wsb += (size_t)NN * 3 * 4;
    float* vw        = (float*)wsb; wsb += (size_t)NN * 3 * 4;
    float* h         = (float*)wsb; wsb += (size_t)NN * H * 4;
    float* pre_a     = (float*)wsb; wsb += (size_t)NN * H * 4;
    float* pre_b     = (float*)wsb; wsb += (size_t)NN * H * 4;
    float* vel       = (float*)wsb; wsb += (size_t)NN * 4;
    float* m_agg     = (float*)wsb; wsb += (size_t)NN * H * 4;
    float* coord_agg = (float*)wsb; wsb += (size_t)NN * 3 * 4;
    int* cnt         = (int*)wsb;   wsb += (size_t)NN * 4;
    int* off         = (int*)wsb;   wsb += (size_t)(NN + 4) * 4;
    int* cursor      = (int*)wsb;   wsb += (size_t)NN * 4;
    int* sorted      = (int*)wsb;   wsb += (size_t)NE * 4;
    int* rows_s      = (int*)wsb;   wsb += (size_t)NE * 4;
    int* cols_s      = (int*)wsb;   wsb += (size_t)NE * 4;
    float2* ea_s     = (float2*)wsb; wsb += (size_t)NE * 8;

    // CSR build (per call)
    hipMemsetAsync(cnt, 0, (size_t)NN * 4, stream);
    k_count<<<(NE + 255) / 256, 256, 0, stream>>>(edges, cnt);
    k_scan<<<1, 1024, 0, stream>>>(cnt, off, cursor);
    k_scatter<<<(NE + 255) / 256, 256, 0, stream>>>(edges, cursor, sorted);
    k_gather<<<(NE + 255) / 256, 256, 0, stream>>>(sorted, edges, edge_attr,
                                                   rows_s, cols_s, ea_s);

    // weight prepacks
    k_prepack<<<16, 256, 0, stream>>>(e_w2, w2f, 64);
    k_prepack<<<16, 256, 0, stream>>>(c_w1, w1f, 64);
    k_prepack<<<16, 256, 0, stream>>>(e_w1, waf, 64);
    k_prepack<<<16, 256, 0, stream>>>(e_w1 + 64 * 64, wbf, 64);
    k_prepack<<<16, 256, 0, stream>>>(v_w1, wvf, 64);
    k_prepack<<<32, 256, 0, stream>>>(n_w1, nw1f, 128);
    k_prepack<<<16, 256, 0, stream>>>(n_w2, nw2f, 64);

    hipMemcpyAsync(xw, x, (size_t)NN * 3 * 4, hipMemcpyDeviceToDevice, stream);
    hipMemcpyAsync(vw, v, (size_t)NN * 3 * 4, hipMemcpyDeviceToDevice, stream);
    k_embed<<<768, 256, 0, stream>>>(his, emb_w, emb_b, h);

    for (int layer = 0; layer < 3; layer++) {
        hipMemsetAsync(m_agg, 0, (size_t)NN * H * 4, stream);
        hipMemsetAsync(coord_agg, 0, (size_t)NN * 3 * 4, stream);
        k_node_pre_mfma<<<782, 256, 0, stream>>>(
            h, waf, wbf, wvf, v_b1, v_w2, v_b2, pre_a, pre_b, vel);
        k_edge_mfma<<<2048, 256, 0, stream>>>(
            xw, pre_a, pre_b, ea_s, rows_s, cols_s,
            e_w1, e_b1, e_b2, c_b1, c_w2, w2f, w1f, m_agg, coord_agg);
        k_node_post_mfma<<<782, 256, 0, stream>>>(
            h, m_agg, coord_agg, off, vel, nw1f, nw2f, n_b1, n_b2, xw, vw);
    }
    k_pack<<<(NN * 70 + 255) / 256, 256, 0, stream>>>(xw, h, vw, (float*)d_out);
}

// Round 11
// 1330.895 us; speedup vs baseline: 15.5872x; 1.0090x over previous
//
#include <hip/hip_runtime.h>

#define NN 50000
#define NE 1600000
#define H 64
#define NT (NE / 16)
#define NTILE_N (NN / 16)  // 3125 exact

typedef short bf16x8 __attribute__((ext_vector_type(8)));
typedef float f32x4 __attribute__((ext_vector_type(4)));
typedef unsigned uint4v __attribute__((ext_vector_type(4)));

__device__ __forceinline__ float silu_f(float x) {
    return x / (1.0f + __expf(-x));
}
__device__ __forceinline__ float silu_fast(float x) {
    return x * __builtin_amdgcn_rcpf(1.0f + __expf(-x));
}
__device__ __forceinline__ unsigned short f2bf(float f) {
    union { float f; unsigned u; } v; v.f = f;
    unsigned r = v.u + 0x7fffu + ((v.u >> 16) & 1u);
    return (unsigned short)(r >> 16);
}
// packed f32x2 -> bf16x2 (RNE) in one op
__device__ __forceinline__ unsigned cvt_pk_bf16(float lo, float hi) {
    unsigned r;
    asm volatile("v_cvt_pk_bf16_f32 %0, %1, %2" : "=v"(r) : "v"(lo), "v"(hi));
    return r;
}
__device__ __forceinline__ float bfu_lo(unsigned u) {
    union { unsigned x; float f; } c; c.x = u << 16; return c.f;
}
__device__ __forceinline__ float bfu_hi(unsigned u) {
    union { unsigned x; float f; } c; c.x = u & 0xffff0000u; return c.f;
}
union U8 { bf16x8 v; unsigned u[4]; };

// ---------------- CSR build ----------------
__global__ void k_count(const int* __restrict__ edges, int* __restrict__ cnt) {
    int e = blockIdx.x * blockDim.x + threadIdx.x;
    if (e >= NE) return;
    atomicAdd(&cnt[edges[e]], 1);
}

__global__ void k_scan(const int* __restrict__ cnt, int* __restrict__ off,
                       int* __restrict__ cursor) {
    __shared__ int part[1024];
    const int PER = (NN + 1023) / 1024;
    int t = threadIdx.x;
    int base = t * PER;
    int s = 0;
    for (int i = 0; i < PER; i++) {
        int idx = base + i;
        if (idx < NN) s += cnt[idx];
    }
    part[t] = s;
    __syncthreads();
    for (int d = 1; d < 1024; d <<= 1) {
        int tmp = (t >= d) ? part[t - d] : 0;
        __syncthreads();
        part[t] += tmp;
        __syncthreads();
    }
    int run = (t == 0) ? 0 : part[t - 1];
    for (int i = 0; i < PER; i++) {
        int idx = base + i;
        if (idx < NN) {
            off[idx] = run;
            cursor[idx] = run;
            run += cnt[idx];
        }
    }
    if (t == 1023) off[NN] = part[1023];
}

__global__ void k_scatter(const int* __restrict__ edges, int* __restrict__ cursor,
                          int* __restrict__ sorted) {
    int e = blockIdx.x * blockDim.x + threadIdx.x;
    if (e >= NE) return;
    int r = edges[e];
    int p = atomicAdd(&cursor[r], 1);
    sorted[p] = e;
}

__global__ void k_gather(const int* __restrict__ sorted, const int* __restrict__ edges,
                         const float* __restrict__ edge_attr,
                         int* __restrict__ rows_s, int* __restrict__ cols_s,
                         float2* __restrict__ ea_s) {
    int k = blockIdx.x * blockDim.x + threadIdx.x;
    if (k >= NE) return;
    int eid = sorted[k];
    rows_s[k] = edges[eid];
    cols_s[k] = edges[NE + eid];
    ea_s[k] = make_float2(edge_attr[(size_t)eid * 2], edge_attr[(size_t)eid * 2 + 1]);
}

// ---------------- generic weight prepack: [K][64] f32 -> MFMA B-frags bf16 ----------------
__global__ void k_prepack(const float* __restrict__ src, unsigned short* __restrict__ dst,
                          int K) {
    int t = blockIdx.x * blockDim.x + threadIdx.x;
    if (t >= K * 64) return;
    int j = t & 7, lane = (t >> 3) & 63, f = t >> 9;
    int nkc = K >> 5;
    int kc = f % nkc, n = f / nkc;
    int k = kc * 32 + ((lane >> 4) << 3) + j;
    int c = n * 16 + (lane & 15);
    dst[t] = f2bf(src[k * 64 + c]);
}

// ---------------- h = his @ emb_w + emb_b ----------------
__global__ void __launch_bounds__(256) k_embed(
    const float* __restrict__ his, const float* __restrict__ w,
    const float* __restrict__ b, float* __restrict__ h) {
    __shared__ float lw[16 * 64];
    __shared__ float hs[4][16];
    for (int q = threadIdx.x; q < 16 * 64; q += 256) lw[q] = w[q];
    __syncthreads();
    int wv = threadIdx.x >> 6, j = threadIdx.x & 63;
    float bj = b[j];
    for (int n = blockIdx.x * 4 + wv; n < NN; n += gridDim.x * 4) {
        if (j < 16) hs[wv][j] = his[n * 16 + j];
        float acc = bj;
#pragma unroll
        for (int i = 0; i < 16; i++) acc = fmaf(hs[wv][i], lw[i * 64 + j], acc);
        h[(size_t)n * H + j] = acc;
    }
}

// ---------------- MFMA node-pre: pre_a16 = bf16(h@Wa), pre_b16 = bf16(h@Wb), vel ----------------
// D layout: d[n][r] = (node g*4+r, channel n*16+el). Also zeroes m_agg/coord_agg.
__global__ void __launch_bounds__(256, 1) k_node_pre_mfma(
    const float* __restrict__ h,
    const unsigned short* __restrict__ waf, const unsigned short* __restrict__ wbf,
    const unsigned short* __restrict__ wvf,
    const float* __restrict__ v_b1, const float* __restrict__ v_w2,
    const float* __restrict__ v_b2,
    unsigned short* __restrict__ pre_a16, unsigned short* __restrict__ pre_b16,
    float* __restrict__ vel,
    float* __restrict__ m_agg, float* __restrict__ coord_agg) {
    const int w = threadIdx.x >> 6, l = threadIdx.x & 63;
    const int el = l & 15, g = l >> 4;

    bf16x8 wa[4][2], wb[4][2], wv[4][2];
    const bf16x8 *pa = (const bf16x8*)waf, *pb = (const bf16x8*)wbf, *pv = (const bf16x8*)wvf;
#pragma unroll
    for (int n = 0; n < 4; n++)
#pragma unroll
        for (int kc = 0; kc < 2; kc++) {
            wa[n][kc] = pa[(n * 2 + kc) * 64 + l];
            wb[n][kc] = pb[(n * 2 + kc) * 64 + l];
            wv[n][kc] = pv[(n * 2 + kc) * 64 + l];
        }
    float vb1r[4], vw2r[4];
#pragma unroll
    for (int n = 0; n < 4; n++) {
        vb1r[n] = v_b1[n * 16 + el];
        vw2r[n] = v_w2[n * 16 + el];
    }
    float vb2s = v_b2[0];
    f32x4 zero = {0.f, 0.f, 0.f, 0.f};

    int wave = blockIdx.x * 4 + w;
    for (int t = wave; t < NTILE_N; t += gridDim.x * 4) {
        int base = t * 16;
        bf16x8 a[2];
#pragma unroll
        for (int kc = 0; kc < 2; kc++) {
            const float4* src = (const float4*)(h + (size_t)(base + el) * H + kc * 32 + g * 8);
            float4 q0 = src[0], q1 = src[1];
            U8 tu;
            tu.u[0] = cvt_pk_bf16(q0.x, q0.y);
            tu.u[1] = cvt_pk_bf16(q0.z, q0.w);
            tu.u[2] = cvt_pk_bf16(q1.x, q1.y);
            tu.u[3] = cvt_pk_bf16(q1.z, q1.w);
            a[kc] = tu.v;
        }
        f32x4 da[4], db[4], dc[4];
#pragma unroll
        for (int n = 0; n < 4; n++) {
            da[n] = __builtin_amdgcn_mfma_f32_16x16x32_bf16(a[0], wa[n][0], zero, 0, 0, 0);
            da[n] = __builtin_amdgcn_mfma_f32_16x16x32_bf16(a[1], wa[n][1], da[n], 0, 0, 0);
            db[n] = __builtin_amdgcn_mfma_f32_16x16x32_bf16(a[0], wb[n][0], zero, 0, 0, 0);
            db[n] = __builtin_amdgcn_mfma_f32_16x16x32_bf16(a[1], wb[n][1], db[n], 0, 0, 0);
            dc[n] = __builtin_amdgcn_mfma_f32_16x16x32_bf16(a[0], wv[n][0], zero, 0, 0, 0);
            dc[n] = __builtin_amdgcn_mfma_f32_16x16x32_bf16(a[1], wv[n][1], dc[n], 0, 0, 0);
        }
        // store bf16 in (node, channel) orientation
#pragma unroll
        for (int n = 0; n < 4; n++)
#pragma unroll
            for (int r = 0; r < 4; r++) {
                pre_a16[(size_t)(base + g * 4 + r) * H + n * 16 + el] = f2bf(da[n][r]);
                pre_b16[(size_t)(base + g * 4 + r) * H + n * 16 + el] = f2bf(db[n][r]);
            }
        // vel: node g*4+r lives in reg r across the 16 lanes of group g
        float sr[4];
#pragma unroll
        for (int r = 0; r < 4; r++) {
            float s = 0.f;
#pragma unroll
            for (int n = 0; n < 4; n++) s = fmaf(silu_fast(dc[n][r] + vb1r[n]), vw2r[n], s);
#pragma unroll
            for (int mk = 1; mk <= 8; mk <<= 1) s += __shfl_xor(s, mk, 64);
            sr[r] = s;
        }
        if (el == 0) {
#pragma unroll
            for (int r = 0; r < 4; r++) vel[base + g * 4 + r] = sr[r] + vb2s;
        }
        // zero aggregation buffers for this node range (edge kernel runs after)
#pragma unroll
        for (int e = 0; e < 16; e++) m_agg[(size_t)(base + e) * H + l] = 0.f;
        if (l < 48) coord_agg[(base + el) * 3 + (l >> 4)] = 0.f;
    }
}

// ---------------- fused MFMA edge kernel: wave per 16-edge tile ----------------
__global__ void __launch_bounds__(256) k_edge_mfma(
    const float* __restrict__ xw, const unsigned short* __restrict__ pre_a16,
    const unsigned short* __restrict__ pre_b16, const float2* __restrict__ ea_s,
    const int* __restrict__ rows_s, const int* __restrict__ cols_s,
    const float* __restrict__ e_w1, const float* __restrict__ e_b1,
    const float* __restrict__ e_b2, const float* __restrict__ c_b1,
    const float* __restrict__ c_w2,
    const unsigned short* __restrict__ w2f, const unsigned short* __restrict__ w1f,
    float* __restrict__ m_agg, float* __restrict__ coord_agg) {
    __shared__ float lds_m[4][16 * 68];
    __shared__ float lds_t[4][64];
    const int w = threadIdx.x >> 6;
    const int l = threadIdx.x & 63;
    const int el = l & 15;
    const int g = l >> 4;

    bf16x8 w2frag[4][2], w1frag[4][2];
    const bf16x8* w2v = (const bf16x8*)w2f;
    const bf16x8* w1v = (const bf16x8*)w1f;
#pragma unroll
    for (int n = 0; n < 4; n++)
#pragma unroll
        for (int kc = 0; kc < 2; kc++) {
            w2frag[n][kc] = w2v[(n * 2 + kc) * 64 + l];
            w1frag[n][kc] = w1v[(n * 2 + kc) * 64 + l];
        }
    float b2r[4], cb1r[4], cw2r[4];
#pragma unroll
    for (int n = 0; n < 4; n++) {
        b2r[n] = e_b2[n * 16 + el];
        cb1r[n] = c_b1[n * 16 + el];
        cw2r[n] = c_w2[n * 16 + el];
    }
    f32x4 zero = {0.f, 0.f, 0.f, 0.f};
    float* lm = lds_m[w];
    float* lt = lds_t[w];

    // contiguous tile chunk per wave: row locality in L1/L2
    const int nwaves = gridDim.x * 4;
    const int wid = blockIdx.x * 4 + w;
    const int per = (NT + nwaves - 1) / nwaves;
    int t0 = wid * per;
    int t1 = t0 + per;
    if (t1 > NT) t1 = NT;

    for (int t = t0; t < t1; ++t) {
        int base = t * 16;
        int row = rows_s[base + el];
        int col = cols_s[base + el];
        float2 ea = ea_s[base + el];
        float dx = xw[row * 3 + 0] - xw[col * 3 + 0];
        float dy = xw[row * 3 + 1] - xw[col * 3 + 1];
        float dz = xw[row * 3 + 2] - xw[col * 3 + 2];
        float radial = dx * dx + dy * dy + dz * dz;

        bf16x8 a1[2];
#pragma unroll
        for (int kc = 0; kc < 2; kc++) {
            int ch0 = kc * 32 + g * 8;
            const uint4v pav = *(const uint4v*)(pre_a16 + (size_t)row * H + ch0);
            const uint4v pbv = *(const uint4v*)(pre_b16 + (size_t)col * H + ch0);
            const float4* bbr = (const float4*)(e_b1 + ch0);
            const float4* wrr = (const float4*)(e_w1 + 128 * H + ch0);
            const float4* w0r = (const float4*)(e_w1 + 129 * H + ch0);
            const float4* w1r = (const float4*)(e_w1 + 130 * H + ch0);
            float4 bb0 = bbr[0], bb1 = bbr[1], wr0 = wrr[0], wr1 = wrr[1];
            float4 w00 = w0r[0], w01 = w0r[1], w10 = w1r[0], w11 = w1r[1];
            float bb[8] = {bb0.x, bb0.y, bb0.z, bb0.w, bb1.x, bb1.y, bb1.z, bb1.w};
            float wr[8] = {wr0.x, wr0.y, wr0.z, wr0.w, wr1.x, wr1.y, wr1.z, wr1.w};
            float w0[8] = {w00.x, w00.y, w00.z, w00.w, w01.x, w01.y, w01.z, w01.w};
            float w1[8] = {w10.x, w10.y, w10.z, w10.w, w11.x, w11.y, w11.z, w11.w};
            U8 tu;
#pragma unroll
            for (int d = 0; d < 4; d++) {
                float paL = bfu_lo(pav[d]), paH = bfu_hi(pav[d]);
                float pbL = bfu_lo(pbv[d]), pbH = bfu_hi(pbv[d]);
                int j0 = 2 * d, j1 = 2 * d + 1;
                float ttL = paL + pbL + bb[j0];
                ttL = fmaf(radial, wr[j0], ttL);
                ttL = fmaf(ea.x, w0[j0], ttL);
                ttL = fmaf(ea.y, w1[j0], ttL);
                float ttH = paH + pbH + bb[j1];
                ttH = fmaf(radial, wr[j1], ttH);
                ttH = fmaf(ea.x, w0[j1], ttH);
                ttH = fmaf(ea.y, w1[j1], ttH);
                tu.u[d] = cvt_pk_bf16(silu_fast(ttL), silu_fast(ttH));
            }
            a1[kc] = tu.v;
        }

        f32x4 d2[4];
#pragma unroll
        for (int n = 0; n < 4; n++) {
            d2[n] = __builtin_amdgcn_mfma_f32_16x16x32_bf16(a1[0], w2frag[n][0], zero, 0, 0, 0);
            d2[n] = __builtin_amdgcn_mfma_f32_16x16x32_bf16(a1[1], w2frag[n][1], d2[n], 0, 0, 0);
        }
#pragma unroll
        for (int n = 0; n < 4; n++)
#pragma unroll
            for (int r = 0; r < 4; r++)
                lm[(g * 4 + r) * 68 + n * 16 + el] = silu_fast(d2[n][r] + b2r[n]);
        asm volatile("s_waitcnt lgkmcnt(0)" ::: "memory");

        bf16x8 a3[2];
#pragma unroll
        for (int kc = 0; kc < 2; kc++) {
            const float4* q = (const float4*)(lm + el * 68 + kc * 32 + g * 8);
            float4 q0 = q[0], q1 = q[1];
            U8 tu;
            tu.u[0] = cvt_pk_bf16(q0.x, q0.y);
            tu.u[1] = cvt_pk_bf16(q0.z, q0.w);
            tu.u[2] = cvt_pk_bf16(q1.x, q1.y);
            tu.u[3] = cvt_pk_bf16(q1.z, q1.w);
            a3[kc] = tu.v;
        }
        f32x4 d3[4];
#pragma unroll
        for (int n = 0; n < 4; n++) {
            d3[n] = __builtin_amdgcn_mfma_f32_16x16x32_bf16(a3[0], w1frag[n][0], zero, 0, 0, 0);
            d3[n] = __builtin_amdgcn_mfma_f32_16x16x32_bf16(a3[1], w1frag[n][1], d3[n], 0, 0, 0);
        }
        float p[4];
#pragma unroll
        for (int r = 0; r < 4; r++) {
            float pp = 0.f;
#pragma unroll
            for (int n = 0; n < 4; n++) pp = fmaf(silu_fast(d3[n][r] + cb1r[n]), cw2r[n], pp);
#pragma unroll
            for (int mk = 1; mk <= 8; mk <<= 1) pp += __shfl_xor(pp, mk, 64);
            p[r] = pp;
        }
#pragma unroll
        for (int r = 0; r < 4; r++) {
            int ep = g * 4 + r;
            float tx = __shfl(dx, ep, 64) * p[r];
            float ty = __shfl(dy, ep, 64) * p[r];
            float tz = __shfl(dz, ep, 64) * p[r];
            if (el < 3) lt[ep * 4 + el] = (el == 0) ? tx : ((el == 1) ? ty : tz);
        }
        asm volatile("s_waitcnt lgkmcnt(0)" ::: "memory");

        float acc = 0.f, tacc = 0.f;
        int prev = __shfl(row, 0, 64);
#pragma unroll
        for (int e = 0; e < 16; e++) {
            int re = __shfl(row, e, 64);
            if (re != prev) {
                atomicAdd(&m_agg[(size_t)prev * H + l], acc);
                if (l < 3) atomicAdd(&coord_agg[prev * 3 + l], tacc);
                acc = 0.f;
                tacc = 0.f;
                prev = re;
            }
            acc += lm[e * 68 + l];
            if (l < 3) tacc += lt[e * 4 + l];
        }
        atomicAdd(&m_agg[(size_t)prev * H + l], acc);
        if (l < 3) atomicAdd(&coord_agg[prev * 3 + l], tacc);
    }
}

// ---------------- MFMA node-post: node MLP + h recurrence + x/v update ----------------
// D layout: d[n][r] = (node g*4+r, channel n*16+el)
__global__ void __launch_bounds__(256, 1) k_node_post_mfma(
    float* __restrict__ h, const float* __restrict__ m_agg,
    const float* __restrict__ coord_agg, const int* __restrict__ off,
    const float* __restrict__ vel,
    const unsigned short* __restrict__ nw1f, const unsigned short* __restrict__ nw2f,
    const float* __restrict__ n_b1, const float* __restrict__ n_b2,
    float* __restrict__ xw, float* __restrict__ vw) {
    __shared__ float st_all[4][16 * 68];
    const int w = threadIdx.x >> 6, l = threadIdx.x & 63;
    const int el = l & 15, g = l >> 4;
    float* st = st_all[w];

    bf16x8 w1n[4][4], w2n[4][2];
    const bf16x8* p1 = (const bf16x8*)nw1f;
    const bf16x8* p2 = (const bf16x8*)nw2f;
#pragma unroll
    for (int n = 0; n < 4; n++) {
#pragma unroll
        for (int kc = 0; kc < 4; kc++) w1n[n][kc] = p1[(n * 4 + kc) * 64 + l];
#pragma unroll
        for (int kc = 0; kc < 2; kc++) w2n[n][kc] = p2[(n * 2 + kc) * 64 + l];
    }
    float b1r[4], b2r[4];
#pragma unroll
    for (int n = 0; n < 4; n++) {
        b1r[n] = n_b1[n * 16 + el];
        b2r[n] = n_b2[n * 16 + el];
    }
    f32x4 zero = {0.f, 0.f, 0.f, 0.f};

    int wave = blockIdx.x * 4 + w;
    for (int t = wave; t < NTILE_N; t += gridDim.x * 4) {
        int base = t * 16;
        bf16x8 a1[4];
#pragma unroll
        for (int kc = 0; kc < 4; kc++) {
            const float* srcp = (kc < 2)
                ? (h + (size_t)(base + el) * H + kc * 32 + g * 8)
                : (m_agg + (size_t)(base + el) * H + (kc - 2) * 32 + g * 8);
            const float4* src = (const float4*)srcp;
            float4 q0 = src[0], q1 = src[1];
            U8 tu;
            tu.u[0] = cvt_pk_bf16(q0.x, q0.y);
            tu.u[1] = cvt_pk_bf16(q0.z, q0.w);
            tu.u[2] = cvt_pk_bf16(q1.x, q1.y);
            tu.u[3] = cvt_pk_bf16(q1.z, q1.w);
            a1[kc] = tu.v;
        }
        f32x4 d1[4];
#pragma unroll
        for (int n = 0; n < 4; n++) {
            d1[n] = __builtin_amdgcn_mfma_f32_16x16x32_bf16(a1[0], w1n[n][0], zero, 0, 0, 0);
            d1[n] = __builtin_amdgcn_mfma_f32_16x16x32_bf16(a1[1], w1n[n][1], d1[n], 0, 0, 0);
            d1[n] = __builtin_amdgcn_mfma_f32_16x16x32_bf16(a1[2], w1n[n][2], d1[n], 0, 0, 0);
            d1[n] = __builtin_amdgcn_mfma_f32_16x16x32_bf16(a1[3], w1n[n][3], d1[n], 0, 0, 0);
        }
#pragma unroll
        for (int n = 0; n < 4; n++)
#pragma unroll
            for (int r = 0; r < 4; r++)
                st[(g * 4 + r) * 68 + n * 16 + el] = silu_fast(d1[n][r] + b1r[n]);
        asm volatile("s_waitcnt lgkmcnt(0)" ::: "memory");

        bf16x8 a2[2];
#pragma unroll
        for (int kc = 0; kc < 2; kc++) {
            const float4* q = (const float4*)(st + el * 68 + kc * 32 + g * 8);
            float4 q0 = q[0], q1 = q[1];
            U8 tu;
            tu.u[0] = cvt_pk_bf16(q0.x, q0.y);
            tu.u[1] = cvt_pk_bf16(q0.z, q0.w);
            tu.u[2] = cvt_pk_bf16(q1.x, q1.y);
            tu.u[3] = cvt_pk_bf16(q1.z, q1.w);
            a2[kc] = tu.v;
        }
        f32x4 d2[4];
#pragma unroll
        for (int n = 0; n < 4; n++) {
            d2[n] = __builtin_amdgcn_mfma_f32_16x16x32_bf16(a2[0], w2n[n][0], zero, 0, 0, 0);
            d2[n] = __builtin_amdgcn_mfma_f32_16x16x32_bf16(a2[1], w2n[n][1], d2[n], 0, 0, 0);
        }
#pragma unroll
        for (int n = 0; n < 4; n++)
#pragma unroll
            for (int r = 0; r < 4; r++)
                st[(g * 4 + r) * 68 + n * 16 + el] = d2[n][r] + b2r[n];
        asm volatile("s_waitcnt lgkmcnt(0)" ::: "memory");
#pragma unroll
        for (int e = 0; e < 16; e++) {
            size_t idx = (size_t)(base + e) * H + l;
            h[idx] = 2.f * h[idx] + st[e * 68 + l];
        }
        if (l < 48) {
            int c = l >> 4;
            int node = base + el;
            float deg = fmaxf((float)(off[node + 1] - off[node]), 1.0f);
            float vv = vw[node * 3 + c];
            vv = vv + coord_agg[node * 3 + c] / deg + vel[node] * vv;
            vw[node * 3 + c] = vv;
            xw[node * 3 + c] += vv;
        }
    }
}

// ---------------- pack outputs: x | h | v ----------------
__global__ void k_pack(const float* __restrict__ xw, const float* __restrict__ h,
                       const float* __restrict__ vw, float* __restrict__ out) {
    int t = blockIdx.x * blockDim.x + threadIdx.x;
    if (t >= NN * 70) return;
    if (t < NN * 3) out[t] = xw[t];
    else if (t < NN * 3 + NN * H) out[t] = h[t - NN * 3];
    else out[t] = vw[t - (NN * 3 + NN * H)];
}

extern "C" void kernel_launch(void* const* d_in, const int* in_sizes, int n_in,
                              void* d_out, int out_size, void* d_ws, size_t ws_size,
                              hipStream_t stream) {
    const float* his       = (const float*)d_in[0];
    const float* x         = (const float*)d_in[1];
    const float* v         = (const float*)d_in[2];
    const float* edge_attr = (const float*)d_in[3];
    const int*   edges     = (const int*)d_in[4];
    const float* emb_w = (const float*)d_in[5];
    const float* emb_b = (const float*)d_in[6];
    const float* e_w1  = (const float*)d_in[7];
    const float* e_b1  = (const float*)d_in[8];
    const float* e_w2  = (const float*)d_in[9];
    const float* e_b2  = (const float*)d_in[10];
    const float* c_w1  = (const float*)d_in[11];
    const float* c_b1  = (const float*)d_in[12];
    const float* c_w2  = (const float*)d_in[13];
    const float* n_w1  = (const float*)d_in[14];
    const float* n_b1  = (const float*)d_in[15];
    const float* n_w2  = (const float*)d_in[16];
    const float* n_b2  = (const float*)d_in[17];
    const float* v_w1  = (const float*)d_in[18];
    const float* v_b1  = (const float*)d_in[19];
    const float* v_w2  = (const float*)d_in[20];
    const float* v_b2  = (const float*)d_in[21];

    char* wsb = (char*)d_ws;
    unsigned short* w2f  = (unsigned short*)wsb; wsb += 8192;
    unsigned short* w1f  = (unsigned short*)wsb; wsb += 8192;
    unsigned short* waf  = (unsigned short*)wsb; wsb += 8192;
    unsigned short* wbf  = (unsigned short*)wsb; wsb += 8192;
    unsigned short* wvf  = (unsigned short*)wsb; wsb += 8192;
    unsigned short* nw1f = (unsigned short*)wsb; wsb += 16384;
    unsigned short* nw2f = (unsigned short*)wsb; wsb += 8192;
    float* xw        = (float*)wsb; wsb += (size_t)NN * 3 * 4;
    float* vw        = (float*)wsb; wsb += (size_t)NN * 3 * 4;
    float* h         = (float*)wsb; wsb += (size_t)NN * H * 4;
    unsigned short* pre_a16 = (unsigned short*)wsb; wsb += (size_t)NN * H * 2;
    unsigned short* pre_b16 = (unsigned short*)wsb; wsb += (size_t)NN * H * 2;
    float* vel       = (float*)wsb; wsb += (size_t)NN * 4;
    float* m_agg     = (float*)wsb; wsb += (size_t)NN * H * 4;
    float* coord_agg = (float*)wsb; wsb += (size_t)NN * 3 * 4;
    int* cnt         = (int*)wsb;   wsb += (size_t)NN * 4;
    int* off         = (int*)wsb;   wsb += (size_t)(NN + 4) * 4;
    int* cursor      = (int*)wsb;   wsb += (size_t)NN * 4;
    int* sorted      = (int*)wsb;   wsb += (size_t)NE * 4;
    int* rows_s      = (int*)wsb;   wsb += (size_t)NE * 4;
    int* cols_s      = (int*)wsb;   wsb += (size_t)NE * 4;
    float2* ea_s     = (float2*)wsb; wsb += (size_t)NE * 8;

    // CSR build (per call)
    hipMemsetAsync(cnt, 0, (size_t)NN * 4, stream);
    k_count<<<(NE + 255) / 256, 256, 0, stream>>>(edges, cnt);
    k_scan<<<1, 1024, 0, stream>>>(cnt, off, cursor);
    k_scatter<<<(NE + 255) / 256, 256, 0, stream>>>(edges, cursor, sorted);
    k_gather<<<(NE + 255) / 256, 256, 0, stream>>>(sorted, edges, edge_attr,
                                                   rows_s, cols_s, ea_s);

    // weight prepacks
    k_prepack<<<16, 256, 0, stream>>>(e_w2, w2f, 64);
    k_prepack<<<16, 256, 0, stream>>>(c_w1, w1f, 64);
    k_prepack<<<16, 256, 0, stream>>>(e_w1, waf, 64);
    k_prepack<<<16, 256, 0, stream>>>(e_w1 + 64 * 64, wbf, 64);
    k_prepack<<<16, 256, 0, stream>>>(v_w1, wvf, 64);
    k_prepack<<<32, 256, 0, stream>>>(n_w1, nw1f, 128);
    k_prepack<<<16, 256, 0, stream>>>(n_w2, nw2f, 64);

    hipMemcpyAsync(xw, x, (size_t)NN * 3 * 4, hipMemcpyDeviceToDevice, stream);
    hipMemcpyAsync(vw, v, (size_t)NN * 3 * 4, hipMemcpyDeviceToDevice, stream);
    k_embed<<<768, 256, 0, stream>>>(his, emb_w, emb_b, h);

    for (int layer = 0; layer < 3; layer++) {
        k_node_pre_mfma<<<782, 256, 0, stream>>>(
            h, waf, wbf, wvf, v_b1, v_w2, v_b2, pre_a16, pre_b16, vel,
            m_agg, coord_agg);
        k_edge_mfma<<<2048, 256, 0, stream>>>(
            xw, pre_a16, pre_b16, ea_s, rows_s, cols_s,
            e_w1, e_b1, e_b2, c_b1, c_w2, w2f, w1f, m_agg, coord_agg);
        k_node_post_mfma<<<782, 256, 0, stream>>>(
            h, m_agg, coord_agg, off, vel, nw1f, nw2f, n_b1, n_b2, xw, vw);
    }
    k_pack<<<(NN * 70 + 255) / 256, 256, 0, stream>>>(xw, h, vw, (float*)d_out);
}

// Round 13
// 1105.006 us; speedup vs baseline: 18.7735x; 1.2044x over previous
//
#include <hip/hip_runtime.h>

#define NN 50000
#define NE 1600000
#define H 64
#define NT (NE / 16)
#define NTILE_N (NN / 16)  // 3125 exact

typedef short bf16x8 __attribute__((ext_vector_type(8)));
typedef float f32x4 __attribute__((ext_vector_type(4)));
typedef unsigned uint4v __attribute__((ext_vector_type(4)));

__device__ __forceinline__ float silu_f(float x) {
    return x / (1.0f + __expf(-x));
}
__device__ __forceinline__ float silu_fast(float x) {
    return x * __builtin_amdgcn_rcpf(1.0f + __expf(-x));
}
__device__ __forceinline__ unsigned short f2bf(float f) {
    union { float f; unsigned u; } v; v.f = f;
    unsigned r = v.u + 0x7fffu + ((v.u >> 16) & 1u);
    return (unsigned short)(r >> 16);
}
// packed f32x2 -> bf16x2 (RNE) in one op
__device__ __forceinline__ unsigned cvt_pk_bf16(float lo, float hi) {
    unsigned r;
    asm volatile("v_cvt_pk_bf16_f32 %0, %1, %2" : "=v"(r) : "v"(lo), "v"(hi));
    return r;
}
__device__ __forceinline__ float bfu_lo(unsigned u) {
    union { unsigned x; float f; } c; c.x = u << 16; return c.f;
}
__device__ __forceinline__ float bfu_hi(unsigned u) {
    union { unsigned x; float f; } c; c.x = u & 0xffff0000u; return c.f;
}
union U8 { bf16x8 v; unsigned u[4]; };

// ---------------- CSR build ----------------
__global__ void k_count(const int* __restrict__ edges, int* __restrict__ cnt) {
    int e = blockIdx.x * blockDim.x + threadIdx.x;
    if (e >= NE) return;
    atomicAdd(&cnt[edges[e]], 1);
}

__global__ void k_scan(const int* __restrict__ cnt, int* __restrict__ off,
                       int* __restrict__ cursor) {
    __shared__ int part[1024];
    const int PER = (NN + 1023) / 1024;
    int t = threadIdx.x;
    int base = t * PER;
    int s = 0;
    for (int i = 0; i < PER; i++) {
        int idx = base + i;
        if (idx < NN) s += cnt[idx];
    }
    part[t] = s;
    __syncthreads();
    for (int d = 1; d < 1024; d <<= 1) {
        int tmp = (t >= d) ? part[t - d] : 0;
        __syncthreads();
        part[t] += tmp;
        __syncthreads();
    }
    int run = (t == 0) ? 0 : part[t - 1];
    for (int i = 0; i < PER; i++) {
        int idx = base + i;
        if (idx < NN) {
            off[idx] = run;
            cursor[idx] = run;
            run += cnt[idx];
        }
    }
    if (t == 1023) off[NN] = part[1023];
}

__global__ void k_scatter(const int* __restrict__ edges, int* __restrict__ cursor,
                          int* __restrict__ sorted) {
    int e = blockIdx.x * blockDim.x + threadIdx.x;
    if (e >= NE) return;
    int r = edges[e];
    int p = atomicAdd(&cursor[r], 1);
    sorted[p] = e;
}

__global__ void k_gather(const int* __restrict__ sorted, const int* __restrict__ edges,
                         const float* __restrict__ edge_attr,
                         int* __restrict__ rows_s, int* __restrict__ cols_s,
                         float2* __restrict__ ea_s) {
    int k = blockIdx.x * blockDim.x + threadIdx.x;
    if (k >= NE) return;
    int eid = sorted[k];
    rows_s[k] = edges[eid];
    cols_s[k] = edges[NE + eid];
    ea_s[k] = make_float2(edge_attr[(size_t)eid * 2], edge_attr[(size_t)eid * 2 + 1]);
}

// ---------------- generic weight prepack: [K][64] f32 -> MFMA B-frags bf16 ----------------
__global__ void k_prepack(const float* __restrict__ src, unsigned short* __restrict__ dst,
                          int K) {
    int t = blockIdx.x * blockDim.x + threadIdx.x;
    if (t >= K * 64) return;
    int j = t & 7, lane = (t >> 3) & 63, f = t >> 9;
    int nkc = K >> 5;
    int kc = f % nkc, n = f / nkc;
    int k = kc * 32 + ((lane >> 4) << 3) + j;
    int c = n * 16 + (lane & 15);
    dst[t] = f2bf(src[k * 64 + c]);
}

// ---------------- h = his @ emb_w + emb_b ----------------
__global__ void __launch_bounds__(256) k_embed(
    const float* __restrict__ his, const float* __restrict__ w,
    const float* __restrict__ b, float* __restrict__ h) {
    __shared__ float lw[16 * 64];
    __shared__ float hs[4][16];
    for (int q = threadIdx.x; q < 16 * 64; q += 256) lw[q] = w[q];
    __syncthreads();
    int wv = threadIdx.x >> 6, j = threadIdx.x & 63;
    float bj = b[j];
    for (int n = blockIdx.x * 4 + wv; n < NN; n += gridDim.x * 4) {
        if (j < 16) hs[wv][j] = his[n * 16 + j];
        float acc = bj;
#pragma unroll
        for (int i = 0; i < 16; i++) acc = fmaf(hs[wv][i], lw[i * 64 + j], acc);
        h[(size_t)n * H + j] = acc;
    }
}

// ---------------- MFMA node-pre: pre_a16 = bf16(h@Wa), pre_b16 = bf16(h@Wb), vel ----------------
// D layout: d[n][r] = (node g*4+r, channel n*16+el). Also zeroes m_agg/coord_agg.
__global__ void __launch_bounds__(256, 1) k_node_pre_mfma(
    const float* __restrict__ h,
    const unsigned short* __restrict__ waf, const unsigned short* __restrict__ wbf,
    const unsigned short* __restrict__ wvf,
    const float* __restrict__ v_b1, const float* __restrict__ v_w2,
    const float* __restrict__ v_b2,
    unsigned short* __restrict__ pre_a16, unsigned short* __restrict__ pre_b16,
    float* __restrict__ vel,
    float* __restrict__ m_agg, float* __restrict__ coord_agg) {
    const int w = threadIdx.x >> 6, l = threadIdx.x & 63;
    const int el = l & 15, g = l >> 4;

    bf16x8 wa[4][2], wb[4][2], wv[4][2];
    const bf16x8 *pa = (const bf16x8*)waf, *pb = (const bf16x8*)wbf, *pv = (const bf16x8*)wvf;
#pragma unroll
    for (int n = 0; n < 4; n++)
#pragma unroll
        for (int kc = 0; kc < 2; kc++) {
            wa[n][kc] = pa[(n * 2 + kc) * 64 + l];
            wb[n][kc] = pb[(n * 2 + kc) * 64 + l];
            wv[n][kc] = pv[(n * 2 + kc) * 64 + l];
        }
    float vb1r[4], vw2r[4];
#pragma unroll
    for (int n = 0; n < 4; n++) {
        vb1r[n] = v_b1[n * 16 + el];
        vw2r[n] = v_w2[n * 16 + el];
    }
    float vb2s = v_b2[0];
    f32x4 zero = {0.f, 0.f, 0.f, 0.f};

    int wave = blockIdx.x * 4 + w;
    for (int t = wave; t < NTILE_N; t += gridDim.x * 4) {
        int base = t * 16;
        bf16x8 a[2];
#pragma unroll
        for (int kc = 0; kc < 2; kc++) {
            const float4* src = (const float4*)(h + (size_t)(base + el) * H + kc * 32 + g * 8);
            float4 q0 = src[0], q1 = src[1];
            U8 tu;
            tu.u[0] = cvt_pk_bf16(q0.x, q0.y);
            tu.u[1] = cvt_pk_bf16(q0.z, q0.w);
            tu.u[2] = cvt_pk_bf16(q1.x, q1.y);
            tu.u[3] = cvt_pk_bf16(q1.z, q1.w);
            a[kc] = tu.v;
        }
        f32x4 da[4], db[4], dc[4];
#pragma unroll
        for (int n = 0; n < 4; n++) {
            da[n] = __builtin_amdgcn_mfma_f32_16x16x32_bf16(a[0], wa[n][0], zero, 0, 0, 0);
            da[n] = __builtin_amdgcn_mfma_f32_16x16x32_bf16(a[1], wa[n][1], da[n], 0, 0, 0);
            db[n] = __builtin_amdgcn_mfma_f32_16x16x32_bf16(a[0], wb[n][0], zero, 0, 0, 0);
            db[n] = __builtin_amdgcn_mfma_f32_16x16x32_bf16(a[1], wb[n][1], db[n], 0, 0, 0);
            dc[n] = __builtin_amdgcn_mfma_f32_16x16x32_bf16(a[0], wv[n][0], zero, 0, 0, 0);
            dc[n] = __builtin_amdgcn_mfma_f32_16x16x32_bf16(a[1], wv[n][1], dc[n], 0, 0, 0);
        }
        // store bf16 in (node, channel) orientation
#pragma unroll
        for (int n = 0; n < 4; n++)
#pragma unroll
            for (int r = 0; r < 4; r++) {
                pre_a16[(size_t)(base + g * 4 + r) * H + n * 16 + el] = f2bf(da[n][r]);
                pre_b16[(size_t)(base + g * 4 + r) * H + n * 16 + el] = f2bf(db[n][r]);
            }
        // vel: node g*4+r lives in reg r across the 16 lanes of group g
        float sr[4];
#pragma unroll
        for (int r = 0; r < 4; r++) {
            float s = 0.f;
#pragma unroll
            for (int n = 0; n < 4; n++) s = fmaf(silu_fast(dc[n][r] + vb1r[n]), vw2r[n], s);
#pragma unroll
            for (int mk = 1; mk <= 8; mk <<= 1) s += __shfl_xor(s, mk, 64);
            sr[r] = s;
        }
        if (el == 0) {
#pragma unroll
            for (int r = 0; r < 4; r++) vel[base + g * 4 + r] = sr[r] + vb2s;
        }
        // zero aggregation buffers for this node range (edge kernel runs after)
#pragma unroll
        for (int e = 0; e < 16; e++) m_agg[(size_t)(base + e) * H + l] = 0.f;
        if (l < 48) coord_agg[(base + el) * 3 + (l >> 4)] = 0.f;
    }
}

// ---------------- fused MFMA edge kernel: wave per 16-edge tile ----------------
// Weights + stage1 consts live in LDS (block-shared) instead of persistent VGPRs,
// cutting per-thread register pressure to raise occupancy past 2 waves/SIMD.
__global__ void __launch_bounds__(256) k_edge_mfma(
    const float* __restrict__ xw, const unsigned short* __restrict__ pre_a16,
    const unsigned short* __restrict__ pre_b16, const float2* __restrict__ ea_s,
    const int* __restrict__ rows_s, const int* __restrict__ cols_s,
    const float* __restrict__ e_w1, const float* __restrict__ e_b1,
    const float* __restrict__ e_b2, const float* __restrict__ c_b1,
    const float* __restrict__ c_w2,
    const unsigned short* __restrict__ w2f, const unsigned short* __restrict__ w1f,
    float* __restrict__ m_agg, float* __restrict__ coord_agg) {
    __shared__ float lds_m[4][16 * 68];
    __shared__ float lds_t[4][64];
    __shared__ unsigned short w2l[4096];   // 8 KB: e_w2 B-frags
    __shared__ unsigned short w1l[4096];   // 8 KB: c_w1 B-frags
    __shared__ float cst[4 * 64];          // 1 KB: e_b1 | wr | w0 | w1 rows
    const int w = threadIdx.x >> 6;
    const int l = threadIdx.x & 63;
    const int el = l & 15;
    const int g = l >> 4;

    // block-cooperative staging (once)
    {
        const unsigned* s2 = (const unsigned*)w2f;
        const unsigned* s1 = (const unsigned*)w1f;
        unsigned* d2p = (unsigned*)w2l;
        unsigned* d1p = (unsigned*)w1l;
        for (int q = threadIdx.x; q < 2048; q += 256) {
            d2p[q] = s2[q];
            d1p[q] = s1[q];
        }
        if (threadIdx.x < 64) {
            int q = threadIdx.x;
            cst[q] = e_b1[q];
            cst[64 + q] = e_w1[128 * H + q];
            cst[128 + q] = e_w1[129 * H + q];
            cst[192 + q] = e_w1[130 * H + q];
        }
    }
    __syncthreads();

    float b2r[4], cb1r[4], cw2r[4];
#pragma unroll
    for (int n = 0; n < 4; n++) {
        b2r[n] = e_b2[n * 16 + el];
        cb1r[n] = c_b1[n * 16 + el];
        cw2r[n] = c_w2[n * 16 + el];
    }
    f32x4 zero = {0.f, 0.f, 0.f, 0.f};
    float* lm = lds_m[w];
    float* lt = lds_t[w];
    const bf16x8* w2p = (const bf16x8*)w2l;
    const bf16x8* w1p = (const bf16x8*)w1l;

    // contiguous tile chunk per wave: row locality in L1/L2
    const int nwaves = gridDim.x * 4;
    const int wid = blockIdx.x * 4 + w;
    const int per = (NT + nwaves - 1) / nwaves;
    int t0 = wid * per;
    int t1 = t0 + per;
    if (t1 > NT) t1 = NT;

    for (int t = t0; t < t1; ++t) {
        int base = t * 16;
        int row = rows_s[base + el];
        int col = cols_s[base + el];
        float2 ea = ea_s[base + el];
        float dx = xw[row * 3 + 0] - xw[col * 3 + 0];
        float dy = xw[row * 3 + 1] - xw[col * 3 + 1];
        float dz = xw[row * 3 + 2] - xw[col * 3 + 2];
        float radial = dx * dx + dy * dy + dz * dz;

        bf16x8 a1[2];
#pragma unroll
        for (int kc = 0; kc < 2; kc++) {
            int ch0 = kc * 32 + g * 8;
            const uint4v pav = *(const uint4v*)(pre_a16 + (size_t)row * H + ch0);
            const uint4v pbv = *(const uint4v*)(pre_b16 + (size_t)col * H + ch0);
            const float4* bbr = (const float4*)(cst + ch0);
            const float4* wrr = (const float4*)(cst + 64 + ch0);
            const float4* w0r = (const float4*)(cst + 128 + ch0);
            const float4* w1r = (const float4*)(cst + 192 + ch0);
            float4 bb0 = bbr[0], bb1 = bbr[1], wr0 = wrr[0], wr1 = wrr[1];
            float4 w00 = w0r[0], w01 = w0r[1], w10 = w1r[0], w11 = w1r[1];
            float bb[8] = {bb0.x, bb0.y, bb0.z, bb0.w, bb1.x, bb1.y, bb1.z, bb1.w};
            float wr[8] = {wr0.x, wr0.y, wr0.z, wr0.w, wr1.x, wr1.y, wr1.z, wr1.w};
            float w0[8] = {w00.x, w00.y, w00.z, w00.w, w01.x, w01.y, w01.z, w01.w};
            float w1[8] = {w10.x, w10.y, w10.z, w10.w, w11.x, w11.y, w11.z, w11.w};
            U8 tu;
#pragma unroll
            for (int d = 0; d < 4; d++) {
                float paL = bfu_lo(pav[d]), paH = bfu_hi(pav[d]);
                float pbL = bfu_lo(pbv[d]), pbH = bfu_hi(pbv[d]);
                int j0 = 2 * d, j1 = 2 * d + 1;
                float ttL = paL + pbL + bb[j0];
                ttL = fmaf(radial, wr[j0], ttL);
                ttL = fmaf(ea.x, w0[j0], ttL);
                ttL = fmaf(ea.y, w1[j0], ttL);
                float ttH = paH + pbH + bb[j1];
                ttH = fmaf(radial, wr[j1], ttH);
                ttH = fmaf(ea.x, w0[j1], ttH);
                ttH = fmaf(ea.y, w1[j1], ttH);
                tu.u[d] = cvt_pk_bf16(silu_fast(ttL), silu_fast(ttH));
            }
            a1[kc] = tu.v;
        }

        f32x4 d2[4];
#pragma unroll
        for (int n = 0; n < 4; n++) {
            d2[n] = __builtin_amdgcn_mfma_f32_16x16x32_bf16(a1[0], w2p[(n * 2 + 0) * 64 + l], zero, 0, 0, 0);
            d2[n] = __builtin_amdgcn_mfma_f32_16x16x32_bf16(a1[1], w2p[(n * 2 + 1) * 64 + l], d2[n], 0, 0, 0);
        }
#pragma unroll
        for (int n = 0; n < 4; n++)
#pragma unroll
            for (int r = 0; r < 4; r++)
                lm[(g * 4 + r) * 68 + n * 16 + el] = silu_fast(d2[n][r] + b2r[n]);
        asm volatile("s_waitcnt lgkmcnt(0)" ::: "memory");

        bf16x8 a3[2];
#pragma unroll
        for (int kc = 0; kc < 2; kc++) {
            const float4* q = (const float4*)(lm + el * 68 + kc * 32 + g * 8);
            float4 q0 = q[0], q1 = q[1];
            U8 tu;
            tu.u[0] = cvt_pk_bf16(q0.x, q0.y);
            tu.u[1] = cvt_pk_bf16(q0.z, q0.w);
            tu.u[2] = cvt_pk_bf16(q1.x, q1.y);
            tu.u[3] = cvt_pk_bf16(q1.z, q1.w);
            a3[kc] = tu.v;
        }
        f32x4 d3[4];
#pragma unroll
        for (int n = 0; n < 4; n++) {
            d3[n] = __builtin_amdgcn_mfma_f32_16x16x32_bf16(a3[0], w1p[(n * 2 + 0) * 64 + l], zero, 0, 0, 0);
            d3[n] = __builtin_amdgcn_mfma_f32_16x16x32_bf16(a3[1], w1p[(n * 2 + 1) * 64 + l], d3[n], 0, 0, 0);
        }
        float p[4];
#pragma unroll
        for (int r = 0; r < 4; r++) {
            float pp = 0.f;
#pragma unroll
            for (int n = 0; n < 4; n++) pp = fmaf(silu_fast(d3[n][r] + cb1r[n]), cw2r[n], pp);
#pragma unroll
            for (int mk = 1; mk <= 8; mk <<= 1) pp += __shfl_xor(pp, mk, 64);
            p[r] = pp;
        }
#pragma unroll
        for (int r = 0; r < 4; r++) {
            int ep = g * 4 + r;
            float tx = __shfl(dx, ep, 64) * p[r];
            float ty = __shfl(dy, ep, 64) * p[r];
            float tz = __shfl(dz, ep, 64) * p[r];
            if (el < 3) lt[ep * 4 + el] = (el == 0) ? tx : ((el == 1) ? ty : tz);
        }
        asm volatile("s_waitcnt lgkmcnt(0)" ::: "memory");

        float acc = 0.f, tacc = 0.f;
        int prev = __shfl(row, 0, 64);
#pragma unroll
        for (int e = 0; e < 16; e++) {
            int re = __shfl(row, e, 64);
            if (re != prev) {
                atomicAdd(&m_agg[(size_t)prev * H + l], acc);
                if (l < 3) atomicAdd(&coord_agg[prev * 3 + l], tacc);
                acc = 0.f;
                tacc = 0.f;
                prev = re;
            }
            acc += lm[e * 68 + l];
            if (l < 3) tacc += lt[e * 4 + l];
        }
        atomicAdd(&m_agg[(size_t)prev * H + l], acc);
        if (l < 3) atomicAdd(&coord_agg[prev * 3 + l], tacc);
    }
}

// ---------------- MFMA node-post: node MLP + h recurrence + x/v update ----------------
// D layout: d[n][r] = (node g*4+r, channel n*16+el)
__global__ void __launch_bounds__(256, 1) k_node_post_mfma(
    float* __restrict__ h, const float* __restrict__ m_agg,
    const float* __restrict__ coord_agg, const int* __restrict__ off,
    const float* __restrict__ vel,
    const unsigned short* __restrict__ nw1f, const unsigned short* __restrict__ nw2f,
    const float* __restrict__ n_b1, const float* __restrict__ n_b2,
    float* __restrict__ xw, float* __restrict__ vw) {
    __shared__ float st_all[4][16 * 68];
    const int w = threadIdx.x >> 6, l = threadIdx.x & 63;
    const int el = l & 15, g = l >> 4;
    float* st = st_all[w];

    bf16x8 w1n[4][4], w2n[4][2];
    const bf16x8* p1 = (const bf16x8*)nw1f;
    const bf16x8* p2 = (const bf16x8*)nw2f;
#pragma unroll
    for (int n = 0; n < 4; n++) {
#pragma unroll
        for (int kc = 0; kc < 4; kc++) w1n[n][kc] = p1[(n * 4 + kc) * 64 + l];
#pragma unroll
        for (int kc = 0; kc < 2; kc++) w2n[n][kc] = p2[(n * 2 + kc) * 64 + l];
    }
    float b1r[4], b2r[4];
#pragma unroll
    for (int n = 0; n < 4; n++) {
        b1r[n] = n_b1[n * 16 + el];
        b2r[n] = n_b2[n * 16 + el];
    }
    f32x4 zero = {0.f, 0.f, 0.f, 0.f};

    int wave = blockIdx.x * 4 + w;
    for (int t = wave; t < NTILE_N; t += gridDim.x * 4) {
        int base = t * 16;
        bf16x8 a1[4];
#pragma unroll
        for (int kc = 0; kc < 4; kc++) {
            const float* srcp = (kc < 2)
                ? (h + (size_t)(base + el) * H + kc * 32 + g * 8)
                : (m_agg + (size_t)(base + el) * H + (kc - 2) * 32 + g * 8);
            const float4* src = (const float4*)srcp;
            float4 q0 = src[0], q1 = src[1];
            U8 tu;
            tu.u[0] = cvt_pk_bf16(q0.x, q0.y);
            tu.u[1] = cvt_pk_bf16(q0.z, q0.w);
            tu.u[2] = cvt_pk_bf16(q1.x, q1.y);
            tu.u[3] = cvt_pk_bf16(q1.z, q1.w);
            a1[kc] = tu.v;
        }
        f32x4 d1[4];
#pragma unroll
        for (int n = 0; n < 4; n++) {
            d1[n] = __builtin_amdgcn_mfma_f32_16x16x32_bf16(a1[0], w1n[n][0], zero, 0, 0, 0);
            d1[n] = __builtin_amdgcn_mfma_f32_16x16x32_bf16(a1[1], w1n[n][1], d1[n], 0, 0, 0);
            d1[n] = __builtin_amdgcn_mfma_f32_16x16x32_bf16(a1[2], w1n[n][2], d1[n], 0, 0, 0);
            d1[n] = __builtin_amdgcn_mfma_f32_16x16x32_bf16(a1[3], w1n[n][3], d1[n], 0, 0, 0);
        }
#pragma unroll
        for (int n = 0; n < 4; n++)
#pragma unroll
            for (int r = 0; r < 4; r++)
                st[(g * 4 + r) * 68 + n * 16 + el] = silu_fast(d1[n][r] + b1r[n]);
        asm volatile("s_waitcnt lgkmcnt(0)" ::: "memory");

        bf16x8 a2[2];
#pragma unroll
        for (int kc = 0; kc < 2; kc++) {
            const float4* q = (const float4*)(st + el * 68 + kc * 32 + g * 8);
            float4 q0 = q[0], q1 = q[1];
            U8 tu;
            tu.u[0] = cvt_pk_bf16(q0.x, q0.y);
            tu.u[1] = cvt_pk_bf16(q0.z, q0.w);
            tu.u[2] = cvt_pk_bf16(q1.x, q1.y);
            tu.u[3] = cvt_pk_bf16(q1.z, q1.w);
            a2[kc] = tu.v;
        }
        f32x4 d2[4];
#pragma unroll
        for (int n = 0; n < 4; n++) {
            d2[n] = __builtin_amdgcn_mfma_f32_16x16x32_bf16(a2[0], w2n[n][0], zero, 0, 0, 0);
            d2[n] = __builtin_amdgcn_mfma_f32_16x16x32_bf16(a2[1], w2n[n][1], d2[n], 0, 0, 0);
        }
#pragma unroll
        for (int n = 0; n < 4; n++)
#pragma unroll
            for (int r = 0; r < 4; r++)
                st[(g * 4 + r) * 68 + n * 16 + el] = d2[n][r] + b2r[n];
        asm volatile("s_waitcnt lgkmcnt(0)" ::: "memory");
#pragma unroll
        for (int e = 0; e < 16; e++) {
            size_t idx = (size_t)(base + e) * H + l;
            h[idx] = 2.f * h[idx] + st[e * 68 + l];
        }
        if (l < 48) {
            int c = l >> 4;
            int node = base + el;
            float deg = fmaxf((float)(off[node + 1] - off[node]), 1.0f);
            float vv = vw[node * 3 + c];
            vv = vv + coord_agg[node * 3 + c] / deg + vel[node] * vv;
            vw[node * 3 + c] = vv;
            xw[node * 3 + c] += vv;
        }
    }
}

// ---------------- pack outputs: x | h | v ----------------
__global__ void k_pack(const float* __restrict__ xw, const float* __restrict__ h,
                       const float* __restrict__ vw, float* __restrict__ out) {
    int t = blockIdx.x * blockDim.x + threadIdx.x;
    if (t >= NN * 70) return;
    if (t < NN * 3) out[t] = xw[t];
    else if (t < NN * 3 + NN * H) out[t] = h[t - NN * 3];
    else out[t] = vw[t - (NN * 3 + NN * H)];
}

extern "C" void kernel_launch(void* const* d_in, const int* in_sizes, int n_in,
                              void* d_out, int out_size, void* d_ws, size_t ws_size,
                              hipStream_t stream) {
    const float* his       = (const float*)d_in[0];
    const float* x         = (const float*)d_in[1];
    const float* v         = (const float*)d_in[2];
    const float* edge_attr = (const float*)d_in[3];
    const int*   edges     = (const int*)d_in[4];
    const float* emb_w = (const float*)d_in[5];
    const float* emb_b = (const float*)d_in[6];
    const float* e_w1  = (const float*)d_in[7];
    const float* e_b1  = (const float*)d_in[8];
    const float* e_w2  = (const float*)d_in[9];
    const float* e_b2  = (const float*)d_in[10];
    const float* c_w1  = (const float*)d_in[11];
    const float* c_b1  = (const float*)d_in[12];
    const float* c_w2  = (const float*)d_in[13];
    const float* n_w1  = (const float*)d_in[14];
    const float* n_b1  = (const float*)d_in[15];
    const float* n_w2  = (const float*)d_in[16];
    const float* n_b2  = (const float*)d_in[17];
    const float* v_w1  = (const float*)d_in[18];
    const float* v_b1  = (const float*)d_in[19];
    const float* v_w2  = (const float*)d_in[20];
    const float* v_b2  = (const float*)d_in[21];

    char* wsb = (char*)d_ws;
    unsigned short* w2f  = (unsigned short*)wsb; wsb += 8192;
    unsigned short* w1f  = (unsigned short*)wsb; wsb += 8192;
    unsigned short* waf  = (unsigned short*)wsb; wsb += 8192;
    unsigned short* wbf  = (unsigned short*)wsb; wsb += 8192;
    unsigned short* wvf  = (unsigned short*)wsb; wsb += 8192;
    unsigned short* nw1f = (unsigned short*)wsb; wsb += 16384;
    unsigned short* nw2f = (unsigned short*)wsb; wsb += 8192;
    float* xw        = (float*)wsb; wsb += (size_t)NN * 3 * 4;
    float* vw        = (float*)wsb; wsb += (size_t)NN * 3 * 4;
    float* h         = (float*)wsb; wsb += (size_t)NN * H * 4;
    unsigned short* pre_a16 = (unsigned short*)wsb; wsb += (size_t)NN * H * 2;
    unsigned short* pre_b16 = (unsigned short*)wsb; wsb += (size_t)NN * H * 2;
    float* vel       = (float*)wsb; wsb += (size_t)NN * 4;
    float* m_agg     = (float*)wsb; wsb += (size_t)NN * H * 4;
    float* coord_agg = (float*)wsb; wsb += (size_t)NN * 3 * 4;
    int* cnt         = (int*)wsb;   wsb += (size_t)NN * 4;
    int* off         = (int*)wsb;   wsb += (size_t)(NN + 4) * 4;
    int* cursor      = (int*)wsb;   wsb += (size_t)NN * 4;
    int* sorted      = (int*)wsb;   wsb += (size_t)NE * 4;
    int* rows_s      = (int*)wsb;   wsb += (size_t)NE * 4;
    int* cols_s      = (int*)wsb;   wsb += (size_t)NE * 4;
    float2* ea_s     = (float2*)wsb; wsb += (size_t)NE * 8;

    // CSR build (per call)
    hipMemsetAsync(cnt, 0, (size_t)NN * 4, stream);
    k_count<<<(NE + 255) / 256, 256, 0, stream>>>(edges, cnt);
    k_scan<<<1, 1024, 0, stream>>>(cnt, off, cursor);
    k_scatter<<<(NE + 255) / 256, 256, 0, stream>>>(edges, cursor, sorted);
    k_gather<<<(NE + 255) / 256, 256, 0, stream>>>(sorted, edges, edge_attr,
                                                   rows_s, cols_s, ea_s);

    // weight prepacks
    k_prepack<<<16, 256, 0, stream>>>(e_w2, w2f, 64);
    k_prepack<<<16, 256, 0, stream>>>(c_w1, w1f, 64);
    k_prepack<<<16, 256, 0, stream>>>(e_w1, waf, 64);
    k_prepack<<<16, 256, 0, stream>>>(e_w1 + 64 * 64, wbf, 64);
    k_prepack<<<16, 256, 0, stream>>>(v_w1, wvf, 64);
    k_prepack<<<32, 256, 0, stream>>>(n_w1, nw1f, 128);
    k_prepack<<<16, 256, 0, stream>>>(n_w2, nw2f, 64);

    hipMemcpyAsync(xw, x, (size_t)NN * 3 * 4, hipMemcpyDeviceToDevice, stream);
    hipMemcpyAsync(vw, v, (size_t)NN * 3 * 4, hipMemcpyDeviceToDevice, stream);
    k_embed<<<768, 256, 0, stream>>>(his, emb_w, emb_b, h);

    for (int layer = 0; layer < 3; layer++) {
        k_node_pre_mfma<<<782, 256, 0, stream>>>(
            h, waf, wbf, wvf, v_b1, v_w2, v_b2, pre_a16, pre_b16, vel,
            m_agg, coord_agg);
        k_edge_mfma<<<2048, 256, 0, stream>>>(
            xw, pre_a16, pre_b16, ea_s, rows_s, cols_s,
            e_w1, e_b1, e_b2, c_b1, c_w2, w2f, w1f, m_agg, coord_agg);
        k_node_post_mfma<<<782, 256, 0, stream>>>(
            h, m_agg, coord_agg, off, vel, nw1f, nw2f, n_b1, n_b2, xw, vw);
    }
    k_pack<<<(NN * 70 + 255) / 256, 256, 0, stream>>>(xw, h, vw, (float*)d_out);
}